// Round 13
// baseline (229.210 us; speedup 1.0000x reference)
//
#include <hip/hip_runtime.h>

#define FD 128  // feature dim (H = O = 128)
#define NB 256  // sort buckets / hist blocks

typedef __attribute__((ext_vector_type(8))) short bf16x8;
typedef __attribute__((ext_vector_type(8))) unsigned short u16x8;
typedef __attribute__((ext_vector_type(4))) float f32x4;

__device__ __forceinline__ float lrelu(float x) { return x > 0.f ? x : 0.2f * x; }

__device__ __forceinline__ unsigned short f2bf(float f) {
    unsigned int u = __float_as_uint(f);
    u = (u + 0x7FFFu + ((u >> 16) & 1u)) >> 16;
    return (unsigned short)u;
}
__device__ __forceinline__ float bf2f(unsigned short h) {
    return __uint_as_float((unsigned int)h << 16);
}

// ---------- MFMA GEMM body: C[n,128] = act(A @ W (+ b)) [* dinv], bf16 out ----------
// SCALE: multiply output row by dinv[row] (folds GCN source-normalization into GEMM,
// making the following gather a pure row-sum).
template <bool BIAS_RELU, bool AV, bool AFP32, bool WF32, bool SCALE>
__device__ __forceinline__ void gemm_body(const void* __restrict__ Av,
                                          const void* __restrict__ Wsrc,
                                          const float* __restrict__ b,
                                          unsigned short* __restrict__ C,
                                          const float* __restrict__ av_s,
                                          const float* __restrict__ av_d,
                                          float* asrc, float* adst,
                                          const float* __restrict__ dinv, int n, int bid) {
    __shared__ unsigned short Wt[FD][136];
    if (WF32) {
        const float* W = (const float*)Wsrc;
        for (int idx = threadIdx.x; idx < FD * FD; idx += 512) {
            int k = idx >> 7, j = idx & 127;
            Wt[j][k] = f2bf(W[idx]);
        }
    } else {
        const unsigned short* Wtg = (const unsigned short*)Wsrc;
        #pragma unroll
        for (int it = 0; it < 4; ++it) {
            int idx = (it * 512 + threadIdx.x) * 8;
            int j = idx >> 7, k = idx & 127;
            *(u16x8*)&Wt[j][k] = *(const u16x8*)&Wtg[idx];
        }
    }
    __syncthreads();

    const int wid = threadIdx.x >> 6;
    const int lane = threadIdx.x & 63;
    const int lm = lane & 15;
    const int lh = lane >> 4;
    const int row0 = bid * 128 + wid * 16;

    const int arow = min(row0 + lm, n - 1);
    bf16x8 a0, a1, a2, a3;
    if (AFP32) {
        const float* Ar = (const float*)Av + (size_t)arow * FD + lh * 8;
        #pragma unroll
        for (int kk = 0; kk < 4; ++kk) {
            float4 lo = *(const float4*)(Ar + kk * 32);
            float4 hi = *(const float4*)(Ar + kk * 32 + 4);
            bf16x8 a;
            a[0] = (short)f2bf(lo.x); a[1] = (short)f2bf(lo.y);
            a[2] = (short)f2bf(lo.z); a[3] = (short)f2bf(lo.w);
            a[4] = (short)f2bf(hi.x); a[5] = (short)f2bf(hi.y);
            a[6] = (short)f2bf(hi.z); a[7] = (short)f2bf(hi.w);
            if (kk == 0) a0 = a; else if (kk == 1) a1 = a; else if (kk == 2) a2 = a; else a3 = a;
        }
    } else {
        const unsigned short* Ar = (const unsigned short*)Av + (size_t)arow * FD + lh * 8;
        a0 = *(const bf16x8*)(Ar);
        a1 = *(const bf16x8*)(Ar + 32);
        a2 = *(const bf16x8*)(Ar + 64);
        a3 = *(const bf16x8*)(Ar + 96);
    }

    f32x4 acc[8];
    #pragma unroll
    for (int nt = 0; nt < 8; ++nt) acc[nt] = (f32x4){0.f, 0.f, 0.f, 0.f};

    #pragma unroll
    for (int nt = 0; nt < 8; ++nt) {
        const unsigned short* wp = &Wt[nt * 16 + lm][lh * 8];
        bf16x8 b0 = *(const bf16x8*)(wp);
        bf16x8 b1 = *(const bf16x8*)(wp + 32);
        bf16x8 b2 = *(const bf16x8*)(wp + 64);
        bf16x8 b3 = *(const bf16x8*)(wp + 96);
        acc[nt] = __builtin_amdgcn_mfma_f32_16x16x32_bf16(a0, b0, acc[nt], 0, 0, 0);
        acc[nt] = __builtin_amdgcn_mfma_f32_16x16x32_bf16(a1, b1, acc[nt], 0, 0, 0);
        acc[nt] = __builtin_amdgcn_mfma_f32_16x16x32_bf16(a2, b2, acc[nt], 0, 0, 0);
        acc[nt] = __builtin_amdgcn_mfma_f32_16x16x32_bf16(a3, b3, acc[nt], 0, 0, 0);
    }

    float dv[4];
    if (SCALE) {
        #pragma unroll
        for (int r = 0; r < 4; ++r) {
            const int row = row0 + 4 * lh + r;
            dv[r] = dinv[min(row, n - 1)];
        }
    }

    #pragma unroll
    for (int nt = 0; nt < 8; ++nt) {
        const int c = nt * 16 + lm;
        float bv = 0.f;
        if (BIAS_RELU) bv = b[c];
        #pragma unroll
        for (int r = 0; r < 4; ++r) {
            const int row = row0 + 4 * lh + r;
            float v = acc[nt][r];
            if (BIAS_RELU) v = fmaxf(v + bv, 0.f);
            if (SCALE) v *= dv[r];
            if (row < n) C[(size_t)row * FD + c] = f2bf(v);
        }
    }

    if (AV) {
        float asv[8], adv[8];
        #pragma unroll
        for (int nt = 0; nt < 8; ++nt) {
            asv[nt] = av_s[nt * 16 + lm];
            adv[nt] = av_d[nt * 16 + lm];
        }
        #pragma unroll
        for (int r = 0; r < 4; ++r) {
            float ps = 0.f, pd = 0.f;
            #pragma unroll
            for (int nt = 0; nt < 8; ++nt) {
                ps = fmaf(acc[nt][r], asv[nt], ps);
                pd = fmaf(acc[nt][r], adv[nt], pd);
            }
            #pragma unroll
            for (int m = 1; m < 16; m <<= 1) {
                ps += __shfl_xor(ps, m);
                pd += __shfl_xor(pd, m);
            }
            const int row = row0 + 4 * lh + r;
            if (lm == 0 && row < n) { asrc[row] = ps; adst[row] = pd; }
        }
    }
}

// ---------- mega kernel 0: emb-GEMM | bucket-hist | W cvt | zero ----------
__global__ __launch_bounds__(512) void k_mega0(const float* __restrict__ x,
                                               const float* __restrict__ W_emb,
                                               const float* __restrict__ b_emb,
                                               unsigned short* __restrict__ h0,
                                               const int* __restrict__ dst, int* ghist,
                                               int e, int chunk,
                                               const float* __restrict__ W1,
                                               const float* __restrict__ W2,
                                               const float* __restrict__ Wg,
                                               unsigned short* __restrict__ Wt4,
                                               float* out, int* counters, int n, int gb) {
    const int bx = blockIdx.x;
    if (bx < gb) {
        gemm_body<true, false, true, true, false>(x, W_emb, b_emb, h0,
                                                  nullptr, nullptr, nullptr, nullptr,
                                                  nullptr, n, bx);
        return;
    }
    if (bx < gb + 256) {
        __shared__ int h[256];
        if (threadIdx.x < 256) h[threadIdx.x] = 0;
        __syncthreads();
        const int blk = bx - gb;
        const int i0 = blk * chunk;
        const int i1 = min(i0 + chunk, e);
        for (int i = i0 + threadIdx.x; i < i1; i += 512)
            atomicAdd(&h[dst[i] >> 8], 1);
        __syncthreads();
        if (threadIdx.x < 256) ghist[threadIdx.x * NB + blk] = h[threadIdx.x];
        return;
    }
    if (bx < gb + 256 + 96) {
        const int elem = (bx - gb - 256) * 512 + threadIdx.x;   // [0, 49152)
        const int sel = elem >> 14;
        const int within = elem & 16383;
        const int k = within >> 7, j = within & 127;
        const float* Ws = (sel == 0) ? W1 : (sel == 1) ? W2 : Wg;
        Wt4[sel * FD * FD + j * FD + k] = f2bf(Ws[within]);
        return;
    }
    if (threadIdx.x < 128) out[threadIdx.x] = 0.f;
    if (threadIdx.x == 128) counters[0] = 0;
    if (threadIdx.x == 129) counters[1] = 0;
}

// ---------- standalone GEMM ----------
template <bool AV, bool SCALE>
__global__ __launch_bounds__(512) void k_gemm(const unsigned short* __restrict__ A,
                                              const unsigned short* __restrict__ Wtg,
                                              unsigned short* __restrict__ C,
                                              const float* __restrict__ av_s,
                                              const float* __restrict__ av_d,
                                              float* asrc, float* adst,
                                              const float* __restrict__ dinv, int n) {
    gemm_body<false, AV, false, false, SCALE>(A, Wtg, nullptr, C, av_s, av_d,
                                              asrc, adst, dinv, n, blockIdx.x);
}

// ---------- scan (scan2 folded via last-block) ----------
__global__ __launch_bounds__(256) void k_scan1(const int* __restrict__ v, int* S,
                                               int* bsum, int* counters, int n) {
    __shared__ int lds[256];
    int i = blockIdx.x * 256 + threadIdx.x;
    int x = (i < n) ? v[i] : 0;
    lds[threadIdx.x] = x;
    __syncthreads();
    for (int off = 1; off < 256; off <<= 1) {
        int t = (threadIdx.x >= off) ? lds[threadIdx.x - off] : 0;
        __syncthreads();
        lds[threadIdx.x] += t;
        __syncthreads();
    }
    if (i < n) S[i] = lds[threadIdx.x];
    if (threadIdx.x == 255) bsum[blockIdx.x] = lds[255];
    __threadfence();
    __shared__ int lastflag;
    if (threadIdx.x == 0) {
        int old = atomicAdd(&counters[1], 1);
        lastflag = (old == (int)gridDim.x - 1);
    }
    __syncthreads();
    if (!lastflag) return;
    int bv = atomicAdd(&bsum[threadIdx.x], 0);
    lds[threadIdx.x] = bv;
    __syncthreads();
    for (int off = 1; off < 256; off <<= 1) {
        int t = (threadIdx.x >= off) ? lds[threadIdx.x - off] : 0;
        __syncthreads();
        lds[threadIdx.x] += t;
        __syncthreads();
    }
    bsum[threadIdx.x] = lds[threadIdx.x];
}

// ---------- bucket scatter ----------
__global__ __launch_bounds__(256) void k_bscatter(const int* __restrict__ dst,
                                                  const int* __restrict__ src,
                                                  const int* __restrict__ S,
                                                  const int* __restrict__ gh,
                                                  const int* __restrict__ bsum,
                                                  int* pk, int e, int chunk) {
    __shared__ int cur[256];
    const int t = threadIdx.x;
    const int idx = t * NB + blockIdx.x;
    cur[t] = S[idx] - gh[idx] + ((t > 0) ? bsum[t - 1] : 0);
    __syncthreads();
    const int i0 = blockIdx.x * chunk;
    const int i1 = min(i0 + chunk, e);
    for (int i = i0 + t; i < i1; i += 256) {
        int d = dst[i];
        int s = src[i];
        int pos = atomicAdd(&cur[d >> 8], 1);
        pk[pos] = (d << 16) | s;
    }
}

// ---------- per-bucket finalize ----------
__global__ __launch_bounds__(256) void k_bfinal(const int* __restrict__ pk,
                                                const int* __restrict__ S,
                                                const int* __restrict__ gh,
                                                const int* __restrict__ bsum,
                                                int* cnt, int* rp, float* dinv,
                                                int* col, int e, int n) {
    __shared__ int cl[256];
    __shared__ int sc[256];
    const int b = blockIdx.x;
    const int i0 = b * NB;
    const int base = S[i0] - gh[i0] + ((b > 0) ? bsum[b - 1] : 0);
    int end;
    if (b < 255) {
        const int i1 = (b + 1) * NB;
        end = S[i1] - gh[i1] + bsum[b];
    } else {
        end = e;
    }
    cl[threadIdx.x] = 0;
    __syncthreads();
    for (int j = base + threadIdx.x; j < end; j += 256)
        atomicAdd(&cl[(pk[j] >> 16) & 255], 1);
    __syncthreads();
    sc[threadIdx.x] = cl[threadIdx.x];
    __syncthreads();
    for (int off = 1; off < 256; off <<= 1) {
        int t = (threadIdx.x >= off) ? sc[threadIdx.x - off] : 0;
        __syncthreads();
        sc[threadIdx.x] += t;
        __syncthreads();
    }
    const int c = cl[threadIdx.x];
    const int incl = sc[threadIdx.x];
    const int d = b * 256 + threadIdx.x;
    if (d < n) {
        cnt[d] = c;
        rp[d] = base + incl;
        dinv[d] = rsqrtf((float)c + 1.0f);
    }
    __syncthreads();
    sc[threadIdx.x] = base + incl - c;
    __syncthreads();
    for (int j = base + threadIdx.x; j < end; j += 256) {
        int p = pk[j];
        int pos = atomicAdd(&sc[(p >> 16) & 255], 1);
        col[pos] = p & 0xFFFF;
    }
}

// ---------- fused gather over bf16 rows, bf16 out ----------
// MODE 0 (GCN, dinv pre-folded into m): out[d] = relu( dinv[d] * (m'[d] + sum m'[s]) + bias )
// MODE 1 (GAT): out[d] = ( sum w_sd g[s] ) / ( sum w_sd ), w = __expf(lrelu(asrc[s]+adst[d]))
template <int MODE>
__global__ __launch_bounds__(256) void k_gather(const unsigned short* __restrict__ m,
                                                const int* __restrict__ col,
                                                const int* __restrict__ rp,
                                                const int* __restrict__ cnt,
                                                const float* __restrict__ dinv,
                                                const float* __restrict__ bias,
                                                const float* __restrict__ asrc,
                                                const float* __restrict__ adst,
                                                unsigned short* __restrict__ out, int n) {
    const int wave = threadIdx.x >> 6;
    const int lane = threadIdx.x & 63;
    const int q = lane >> 4;
    const int l16 = lane & 15;
    const int d = blockIdx.x * 4 + wave;
    if (d >= n) return;
    const int c0 = l16 * 8;

    const float ad = (MODE == 1) ? adst[d] : 0.f;

    float acc[8];
    #pragma unroll
    for (int i = 0; i < 8; ++i) acc[i] = 0.f;
    float denom = 0.f;

    if (q == 0) {  // self term
        u16x8 u = *(const u16x8*)(m + (size_t)d * FD + c0);
        if (MODE == 0) {
            #pragma unroll
            for (int i = 0; i < 8; ++i) acc[i] = bf2f(u[i]);
        } else {
            float w = __expf(lrelu(asrc[d] + ad));
            #pragma unroll
            for (int i = 0; i < 8; ++i) acc[i] = w * bf2f(u[i]);
            denom = w;
        }
    }

    const int deg = cnt[d];
    const int beg = rp[d] - deg;
    int j = q;

    for (; j + 12 < deg; j += 16) {
        const int s0 = col[beg + j];
        const int s1 = col[beg + j + 4];
        const int s2 = col[beg + j + 8];
        const int s3 = col[beg + j + 12];
        const u16x8 u0 = *(const u16x8*)(m + (size_t)s0 * FD + c0);
        const u16x8 u1 = *(const u16x8*)(m + (size_t)s1 * FD + c0);
        const u16x8 u2 = *(const u16x8*)(m + (size_t)s2 * FD + c0);
        const u16x8 u3 = *(const u16x8*)(m + (size_t)s3 * FD + c0);
        if (MODE == 0) {
            #pragma unroll
            for (int i = 0; i < 8; ++i)
                acc[i] += (bf2f(u0[i]) + bf2f(u1[i])) + (bf2f(u2[i]) + bf2f(u3[i]));
        } else {
            float w0 = __expf(lrelu(asrc[s0] + ad));
            float w1 = __expf(lrelu(asrc[s1] + ad));
            float w2 = __expf(lrelu(asrc[s2] + ad));
            float w3 = __expf(lrelu(asrc[s3] + ad));
            #pragma unroll
            for (int i = 0; i < 8; ++i) {
                acc[i] = fmaf(w0, bf2f(u0[i]), acc[i]);
                acc[i] = fmaf(w1, bf2f(u1[i]), acc[i]);
                acc[i] = fmaf(w2, bf2f(u2[i]), acc[i]);
                acc[i] = fmaf(w3, bf2f(u3[i]), acc[i]);
            }
            denom += w0 + w1 + w2 + w3;
        }
    }
    for (; j < deg; j += 4) {
        const int s = col[beg + j];
        const u16x8 u = *(const u16x8*)(m + (size_t)s * FD + c0);
        if (MODE == 0) {
            #pragma unroll
            for (int i = 0; i < 8; ++i) acc[i] += bf2f(u[i]);
        } else {
            float w = __expf(lrelu(asrc[s] + ad));
            #pragma unroll
            for (int i = 0; i < 8; ++i) acc[i] = fmaf(w, bf2f(u[i]), acc[i]);
            denom += w;
        }
    }

    #pragma unroll
    for (int i = 0; i < 8; ++i) {
        acc[i] += __shfl_xor(acc[i], 16);
        acc[i] += __shfl_xor(acc[i], 32);
    }
    if (MODE == 1) {
        denom += __shfl_xor(denom, 16);
        denom += __shfl_xor(denom, 32);
    }

    if (q == 0) {
        float o[8];
        if (MODE == 0) {
            const float dd = dinv[d];
            #pragma unroll
            for (int i = 0; i < 8; ++i) o[i] = fmaxf(fmaf(dd, acc[i], bias[c0 + i]), 0.f);
        } else {
            float inv = 1.0f / denom;
            #pragma unroll
            for (int i = 0; i < 8; ++i) o[i] = acc[i] * inv;
        }
        u16x8 ou;
        #pragma unroll
        for (int i = 0; i < 8; ++i) ou[i] = f2bf(o[i]);
        *(u16x8*)(out + (size_t)d * FD + c0) = ou;
    }
}

// ---------- mean over nodes + final scale/bias (coalesced, last-block) ----------
__global__ __launch_bounds__(256) void k_reduce(const unsigned short* __restrict__ val,
                                                float* out, const float* __restrict__ bg,
                                                int* counters, int n, float invn) {
    const int rg = threadIdx.x >> 4;
    const int cg = threadIdx.x & 15;
    const int c0 = cg * 8;
    float acc[8];
    #pragma unroll
    for (int i = 0; i < 8; ++i) acc[i] = 0.f;

    for (int i = blockIdx.x * 16 + rg; i < n; i += gridDim.x * 16) {
        u16x8 u = *(const u16x8*)(val + (size_t)i * FD + c0);
        #pragma unroll
        for (int k = 0; k < 8; ++k) acc[k] += bf2f(u[k]);
    }

    __shared__ float lds[16][129];
    #pragma unroll
    for (int k = 0; k < 8; ++k) lds[rg][c0 + k] = acc[k];
    __syncthreads();
    if (threadIdx.x < 128) {
        float s = 0.f;
        #pragma unroll
        for (int k = 0; k < 16; ++k) s += lds[k][threadIdx.x];
        atomicAdd(&out[threadIdx.x], s);
    }
    __syncthreads();
    __threadfence();
    __shared__ int lastflag;
    if (threadIdx.x == 0) {
        int old = atomicAdd(&counters[0], 1);
        lastflag = (old == (int)gridDim.x - 1);
    }
    __syncthreads();
    if (lastflag) {
        __threadfence();
        if (threadIdx.x < 128) {
            float v = atomicAdd(&out[threadIdx.x], 0.0f);
            out[threadIdx.x] = v * invn + bg[threadIdx.x];
        }
    }
}

// ---------- launch ----------
extern "C" void kernel_launch(void* const* d_in, const int* in_sizes, int n_in,
                              void* d_out, int out_size, void* d_ws, size_t ws_size,
                              hipStream_t stream) {
    const float* x      = (const float*)d_in[0];
    const int*   ei     = (const int*)d_in[1];
    const float* W_emb  = (const float*)d_in[2];
    const float* b_emb  = (const float*)d_in[3];
    const float* W1     = (const float*)d_in[4];
    const float* b1     = (const float*)d_in[5];
    const float* W2     = (const float*)d_in[6];
    const float* b2     = (const float*)d_in[7];
    const float* Wg     = (const float*)d_in[8];
    const float* a_src  = (const float*)d_in[9];
    const float* a_dst  = (const float*)d_in[10];
    const float* bg     = (const float*)d_in[11];

    const int n = in_sizes[0] / FD;   // 50000
    const int e = in_sizes[1] / 2;    // 800000
    const int* src = ei;
    const int* dst = ei + e;

    unsigned short* bufA = (unsigned short*)d_ws;           // n*128 bf16
    unsigned short* bufB = bufA + (size_t)n * FD;           // n*128 bf16
    unsigned short* Wt4  = bufB + (size_t)n * FD;           // 3 * 128*128 bf16
    float* dinv  = (float*)(Wt4 + 3 * FD * FD);
    float* asrc  = dinv + n;
    float* adst  = asrc + n;
    int*   cnt   = (int*)(adst + n);
    int*   rp    = cnt + n;
    int*   col   = rp + n;
    int*   pk    = col + e;
    int*   ghist = pk + e;            // 65536
    int*   Sg    = ghist + NB * 256;  // 65536
    int*   bsum  = Sg + NB * 256;     // 256
    int*   counters = bsum + 256;     // 2

    const dim3 B(256);
    const int chunk  = (e + NB - 1) / NB;
    const int gnode4 = (n + 3) / 4;
    const int gb128  = (n + 127) / 128;   // 391

    // 1) mega0: emb-GEMM | bhist | wcvt | zero
    k_mega0<<<gb128 + 256 + 96 + 1, 512, 0, stream>>>(x, W_emb, b_emb, bufB,
                                                      dst, ghist, e, chunk,
                                                      W1, W2, Wg, Wt4,
                                                      (float*)d_out, counters, n, gb128);
    // 2-4) sort
    k_scan1<<<256, B, 0, stream>>>(ghist, Sg, bsum, counters, NB * 256);
    k_bscatter<<<NB, B, 0, stream>>>(dst, src, Sg, ghist, bsum, pk, e, chunk);
    k_bfinal<<<256, B, 0, stream>>>(pk, Sg, ghist, bsum, cnt, rp, dinv, col, e, n);

    // 5-6) GCN layer 1: m' = dinv * (h0 @ W1); h1 = relu(dinv*sum + b1)
    k_gemm<false, true><<<gb128, 512, 0, stream>>>(bufB, Wt4 + 0 * FD * FD, bufA,
                                                   nullptr, nullptr, nullptr, nullptr, dinv, n);
    k_gather<0><<<gnode4, B, 0, stream>>>(bufA, col, rp, cnt, dinv, b1,
                                          nullptr, nullptr, bufB, n);
    // 7-8) GCN layer 2
    k_gemm<false, true><<<gb128, 512, 0, stream>>>(bufB, Wt4 + 1 * FD * FD, bufA,
                                                   nullptr, nullptr, nullptr, nullptr, dinv, n);
    k_gather<0><<<gnode4, B, 0, stream>>>(bufA, col, rp, cnt, dinv, b2,
                                          nullptr, nullptr, bufB, n);
    // 9-10) GAT
    k_gemm<true, false><<<gb128, 512, 0, stream>>>(bufB, Wt4 + 2 * FD * FD, bufA,
                                                   a_src, a_dst, asrc, adst, nullptr, n);
    k_gather<1><<<gnode4, B, 0, stream>>>(bufA, col, rp, cnt, nullptr, nullptr,
                                          asrc, adst, bufB, n);
    // 11) mean + final
    k_reduce<<<384, B, 0, stream>>>(bufB, (float*)d_out, bg, counters, n, 1.0f / n);
}

// Round 14
// 216.297 us; speedup vs baseline: 1.0597x; 1.0597x over previous
//
#include <hip/hip_runtime.h>

#define FD 128  // feature dim (H = O = 128)
#define NB 256  // sort buckets / hist blocks

typedef __attribute__((ext_vector_type(8))) short bf16x8;
typedef __attribute__((ext_vector_type(8))) unsigned short u16x8;
typedef __attribute__((ext_vector_type(4))) float f32x4;
typedef __attribute__((ext_vector_type(2))) unsigned int u32x2;

__device__ __forceinline__ float lrelu(float x) { return x > 0.f ? x : 0.2f * x; }

__device__ __forceinline__ unsigned short f2bf(float f) {
    unsigned int u = __float_as_uint(f);
    u = (u + 0x7FFFu + ((u >> 16) & 1u)) >> 16;
    return (unsigned short)u;
}
__device__ __forceinline__ float bf2f(unsigned short h) {
    return __uint_as_float((unsigned int)h << 16);
}
// fp8 e4m3 via gfx950 HW converts
__device__ __forceinline__ unsigned char f2fp8(float f) {
    return (unsigned char)(__builtin_amdgcn_cvt_pk_fp8_f32(f, f, 0, false) & 0xFF);
}

// ---------- MFMA GEMM body: C[n,128] = act(A @ W (+ b)) [* dinv] ----------
// C8: fp8 e4m3 output (feeds gathers); else bf16.
// SCALE: multiply output row by dinv[row] (GCN source-norm folded into GEMM).
template <bool BIAS_RELU, bool AV, bool AFP32, bool WF32, bool SCALE, bool C8>
__device__ __forceinline__ void gemm_body(const void* __restrict__ Av,
                                          const void* __restrict__ Wsrc,
                                          const float* __restrict__ b,
                                          void* __restrict__ C,
                                          const float* __restrict__ av_s,
                                          const float* __restrict__ av_d,
                                          float* asrc, float* adst,
                                          const float* __restrict__ dinv, int n, int bid) {
    __shared__ unsigned short Wt[FD][136];
    if (WF32) {
        const float* W = (const float*)Wsrc;
        for (int idx = threadIdx.x; idx < FD * FD; idx += 512) {
            int k = idx >> 7, j = idx & 127;
            Wt[j][k] = f2bf(W[idx]);
        }
    } else {
        const unsigned short* Wtg = (const unsigned short*)Wsrc;
        #pragma unroll
        for (int it = 0; it < 4; ++it) {
            int idx = (it * 512 + threadIdx.x) * 8;
            int j = idx >> 7, k = idx & 127;
            *(u16x8*)&Wt[j][k] = *(const u16x8*)&Wtg[idx];
        }
    }
    __syncthreads();

    const int wid = threadIdx.x >> 6;
    const int lane = threadIdx.x & 63;
    const int lm = lane & 15;
    const int lh = lane >> 4;
    const int row0 = bid * 128 + wid * 16;

    const int arow = min(row0 + lm, n - 1);
    bf16x8 a0, a1, a2, a3;
    if (AFP32) {
        const float* Ar = (const float*)Av + (size_t)arow * FD + lh * 8;
        #pragma unroll
        for (int kk = 0; kk < 4; ++kk) {
            float4 lo = *(const float4*)(Ar + kk * 32);
            float4 hi = *(const float4*)(Ar + kk * 32 + 4);
            bf16x8 a;
            a[0] = (short)f2bf(lo.x); a[1] = (short)f2bf(lo.y);
            a[2] = (short)f2bf(lo.z); a[3] = (short)f2bf(lo.w);
            a[4] = (short)f2bf(hi.x); a[5] = (short)f2bf(hi.y);
            a[6] = (short)f2bf(hi.z); a[7] = (short)f2bf(hi.w);
            if (kk == 0) a0 = a; else if (kk == 1) a1 = a; else if (kk == 2) a2 = a; else a3 = a;
        }
    } else {
        const unsigned short* Ar = (const unsigned short*)Av + (size_t)arow * FD + lh * 8;
        a0 = *(const bf16x8*)(Ar);
        a1 = *(const bf16x8*)(Ar + 32);
        a2 = *(const bf16x8*)(Ar + 64);
        a3 = *(const bf16x8*)(Ar + 96);
    }

    f32x4 acc[8];
    #pragma unroll
    for (int nt = 0; nt < 8; ++nt) acc[nt] = (f32x4){0.f, 0.f, 0.f, 0.f};

    #pragma unroll
    for (int nt = 0; nt < 8; ++nt) {
        const unsigned short* wp = &Wt[nt * 16 + lm][lh * 8];
        bf16x8 b0 = *(const bf16x8*)(wp);
        bf16x8 b1 = *(const bf16x8*)(wp + 32);
        bf16x8 b2 = *(const bf16x8*)(wp + 64);
        bf16x8 b3 = *(const bf16x8*)(wp + 96);
        acc[nt] = __builtin_amdgcn_mfma_f32_16x16x32_bf16(a0, b0, acc[nt], 0, 0, 0);
        acc[nt] = __builtin_amdgcn_mfma_f32_16x16x32_bf16(a1, b1, acc[nt], 0, 0, 0);
        acc[nt] = __builtin_amdgcn_mfma_f32_16x16x32_bf16(a2, b2, acc[nt], 0, 0, 0);
        acc[nt] = __builtin_amdgcn_mfma_f32_16x16x32_bf16(a3, b3, acc[nt], 0, 0, 0);
    }

    float dv[4];
    if (SCALE) {
        #pragma unroll
        for (int r = 0; r < 4; ++r) {
            const int row = row0 + 4 * lh + r;
            dv[r] = dinv[min(row, n - 1)];
        }
    }

    #pragma unroll
    for (int nt = 0; nt < 8; ++nt) {
        const int c = nt * 16 + lm;
        float bv = 0.f;
        if (BIAS_RELU) bv = b[c];
        #pragma unroll
        for (int r = 0; r < 4; ++r) {
            const int row = row0 + 4 * lh + r;
            float v = acc[nt][r];
            if (BIAS_RELU) v = fmaxf(v + bv, 0.f);
            if (SCALE) v *= dv[r];
            if (row < n) {
                if (C8) ((unsigned char*)C)[(size_t)row * FD + c] = f2fp8(v);
                else    ((unsigned short*)C)[(size_t)row * FD + c] = f2bf(v);
            }
        }
    }

    if (AV) {
        float asv[8], adv[8];
        #pragma unroll
        for (int nt = 0; nt < 8; ++nt) {
            asv[nt] = av_s[nt * 16 + lm];
            adv[nt] = av_d[nt * 16 + lm];
        }
        #pragma unroll
        for (int r = 0; r < 4; ++r) {
            float ps = 0.f, pd = 0.f;
            #pragma unroll
            for (int nt = 0; nt < 8; ++nt) {
                ps = fmaf(acc[nt][r], asv[nt], ps);
                pd = fmaf(acc[nt][r], adv[nt], pd);
            }
            #pragma unroll
            for (int m = 1; m < 16; m <<= 1) {
                ps += __shfl_xor(ps, m);
                pd += __shfl_xor(pd, m);
            }
            const int row = row0 + 4 * lh + r;
            if (lm == 0 && row < n) { asrc[row] = ps; adst[row] = pd; }
        }
    }
}

// ---------- mega kernel 0: emb-GEMM | bucket-hist | W cvt | zero ----------
__global__ __launch_bounds__(512) void k_mega0(const float* __restrict__ x,
                                               const float* __restrict__ W_emb,
                                               const float* __restrict__ b_emb,
                                               unsigned short* __restrict__ h0,
                                               const int* __restrict__ dst, int* ghist,
                                               int e, int chunk,
                                               const float* __restrict__ W1,
                                               const float* __restrict__ W2,
                                               const float* __restrict__ Wg,
                                               unsigned short* __restrict__ Wt4,
                                               float* out, int* counters, int n, int gb) {
    const int bx = blockIdx.x;
    if (bx < gb) {
        gemm_body<true, false, true, true, false, false>(x, W_emb, b_emb, h0,
                                                         nullptr, nullptr, nullptr, nullptr,
                                                         nullptr, n, bx);
        return;
    }
    if (bx < gb + 256) {
        __shared__ int h[256];
        if (threadIdx.x < 256) h[threadIdx.x] = 0;
        __syncthreads();
        const int blk = bx - gb;
        const int i0 = blk * chunk;
        const int i1 = min(i0 + chunk, e);
        for (int i = i0 + threadIdx.x; i < i1; i += 512)
            atomicAdd(&h[dst[i] >> 8], 1);
        __syncthreads();
        if (threadIdx.x < 256) ghist[threadIdx.x * NB + blk] = h[threadIdx.x];
        return;
    }
    if (bx < gb + 256 + 96) {
        const int elem = (bx - gb - 256) * 512 + threadIdx.x;   // [0, 49152)
        const int sel = elem >> 14;
        const int within = elem & 16383;
        const int k = within >> 7, j = within & 127;
        const float* Ws = (sel == 0) ? W1 : (sel == 1) ? W2 : Wg;
        Wt4[sel * FD * FD + j * FD + k] = f2bf(Ws[within]);
        return;
    }
    if (threadIdx.x < 128) out[threadIdx.x] = 0.f;
    if (threadIdx.x == 128) counters[0] = 0;
    if (threadIdx.x == 129) counters[1] = 0;
}

// ---------- standalone GEMM (fp8 out) ----------
template <bool AV, bool SCALE>
__global__ __launch_bounds__(512) void k_gemm(const unsigned short* __restrict__ A,
                                              const unsigned short* __restrict__ Wtg,
                                              unsigned char* __restrict__ C,
                                              const float* __restrict__ av_s,
                                              const float* __restrict__ av_d,
                                              float* asrc, float* adst,
                                              const float* __restrict__ dinv, int n) {
    gemm_body<false, AV, false, false, SCALE, true>(A, Wtg, nullptr, C, av_s, av_d,
                                                    asrc, adst, dinv, n, blockIdx.x);
}

// ---------- scan (scan2 folded via last-block) ----------
__global__ __launch_bounds__(256) void k_scan1(const int* __restrict__ v, int* S,
                                               int* bsum, int* counters, int n) {
    __shared__ int lds[256];
    int i = blockIdx.x * 256 + threadIdx.x;
    int x = (i < n) ? v[i] : 0;
    lds[threadIdx.x] = x;
    __syncthreads();
    for (int off = 1; off < 256; off <<= 1) {
        int t = (threadIdx.x >= off) ? lds[threadIdx.x - off] : 0;
        __syncthreads();
        lds[threadIdx.x] += t;
        __syncthreads();
    }
    if (i < n) S[i] = lds[threadIdx.x];
    if (threadIdx.x == 255) bsum[blockIdx.x] = lds[255];
    __threadfence();
    __shared__ int lastflag;
    if (threadIdx.x == 0) {
        int old = atomicAdd(&counters[1], 1);
        lastflag = (old == (int)gridDim.x - 1);
    }
    __syncthreads();
    if (!lastflag) return;
    int bv = atomicAdd(&bsum[threadIdx.x], 0);
    lds[threadIdx.x] = bv;
    __syncthreads();
    for (int off = 1; off < 256; off <<= 1) {
        int t = (threadIdx.x >= off) ? lds[threadIdx.x - off] : 0;
        __syncthreads();
        lds[threadIdx.x] += t;
        __syncthreads();
    }
    bsum[threadIdx.x] = lds[threadIdx.x];
}

// ---------- bucket scatter ----------
__global__ __launch_bounds__(256) void k_bscatter(const int* __restrict__ dst,
                                                  const int* __restrict__ src,
                                                  const int* __restrict__ S,
                                                  const int* __restrict__ gh,
                                                  const int* __restrict__ bsum,
                                                  int* pk, int e, int chunk) {
    __shared__ int cur[256];
    const int t = threadIdx.x;
    const int idx = t * NB + blockIdx.x;
    cur[t] = S[idx] - gh[idx] + ((t > 0) ? bsum[t - 1] : 0);
    __syncthreads();
    const int i0 = blockIdx.x * chunk;
    const int i1 = min(i0 + chunk, e);
    for (int i = i0 + t; i < i1; i += 256) {
        int d = dst[i];
        int s = src[i];
        int pos = atomicAdd(&cur[d >> 8], 1);
        pk[pos] = (d << 16) | s;
    }
}

// ---------- per-bucket finalize: cnt, rp (segment END), dinv, col (u16) ----------
__global__ __launch_bounds__(256) void k_bfinal(const int* __restrict__ pk,
                                                const int* __restrict__ S,
                                                const int* __restrict__ gh,
                                                const int* __restrict__ bsum,
                                                int* cnt, int* rp, float* dinv,
                                                unsigned short* col, int e, int n) {
    __shared__ int cl[256];
    __shared__ int sc[256];
    const int b = blockIdx.x;
    const int i0 = b * NB;
    const int base = S[i0] - gh[i0] + ((b > 0) ? bsum[b - 1] : 0);
    int end;
    if (b < 255) {
        const int i1 = (b + 1) * NB;
        end = S[i1] - gh[i1] + bsum[b];
    } else {
        end = e;
    }
    cl[threadIdx.x] = 0;
    __syncthreads();
    for (int j = base + threadIdx.x; j < end; j += 256)
        atomicAdd(&cl[(pk[j] >> 16) & 255], 1);
    __syncthreads();
    sc[threadIdx.x] = cl[threadIdx.x];
    __syncthreads();
    for (int off = 1; off < 256; off <<= 1) {
        int t = (threadIdx.x >= off) ? sc[threadIdx.x - off] : 0;
        __syncthreads();
        sc[threadIdx.x] += t;
        __syncthreads();
    }
    const int c = cl[threadIdx.x];
    const int incl = sc[threadIdx.x];
    const int d = b * 256 + threadIdx.x;
    if (d < n) {
        cnt[d] = c;
        rp[d] = base + incl;
        dinv[d] = rsqrtf((float)c + 1.0f);
    }
    __syncthreads();
    sc[threadIdx.x] = base + incl - c;
    __syncthreads();
    for (int j = base + threadIdx.x; j < end; j += 256) {
        int p = pk[j];
        int pos = atomicAdd(&sc[(p >> 16) & 255], 1);
        col[pos] = (unsigned short)(p & 0xFFFF);
    }
}

// ---------- fused gather over fp8 rows, bf16 out ----------
// MODE 0 (GCN, dinv folded into m): out[d] = relu( dinv[d]*(m'[d]+sum m'[s]) + bias )
// MODE 1 (GAT): out[d] = ( sum w_sd g[s] ) / ( sum w_sd ), w = __expf(lrelu(asrc[s]+adst[d]))
template <int MODE>
__global__ __launch_bounds__(256) void k_gather(const unsigned char* __restrict__ m,
                                                const unsigned short* __restrict__ col,
                                                const int* __restrict__ rp,
                                                const int* __restrict__ cnt,
                                                const float* __restrict__ dinv,
                                                const float* __restrict__ bias,
                                                const float* __restrict__ asrc,
                                                const float* __restrict__ adst,
                                                unsigned short* __restrict__ out, int n) {
    const int wave = threadIdx.x >> 6;
    const int lane = threadIdx.x & 63;
    const int q = lane >> 4;
    const int l16 = lane & 15;
    const int d = blockIdx.x * 4 + wave;
    if (d >= n) return;
    const int c0 = l16 * 8;   // byte offset == col offset (1 B/col)

    const float ad = (MODE == 1) ? adst[d] : 0.f;

    float acc[8];
    #pragma unroll
    for (int i = 0; i < 8; ++i) acc[i] = 0.f;
    float denom = 0.f;

    #define UNPK8(w, v)                                                   \
        { auto p0 = __builtin_amdgcn_cvt_pk_f32_fp8((w)[0], false);       \
          auto p1 = __builtin_amdgcn_cvt_pk_f32_fp8((w)[0], true);        \
          auto p2 = __builtin_amdgcn_cvt_pk_f32_fp8((w)[1], false);       \
          auto p3 = __builtin_amdgcn_cvt_pk_f32_fp8((w)[1], true);        \
          v[0] = p0[0]; v[1] = p0[1]; v[2] = p1[0]; v[3] = p1[1];         \
          v[4] = p2[0]; v[5] = p2[1]; v[6] = p3[0]; v[7] = p3[1]; }

    if (q == 0) {  // self term
        u32x2 w = *(const u32x2*)(m + (size_t)d * FD + c0);
        float v[8];
        UNPK8(w, v)
        if (MODE == 0) {
            #pragma unroll
            for (int i = 0; i < 8; ++i) acc[i] = v[i];
        } else {
            float ww = __expf(lrelu(asrc[d] + ad));
            #pragma unroll
            for (int i = 0; i < 8; ++i) acc[i] = ww * v[i];
            denom = ww;
        }
    }

    const int deg = cnt[d];
    const int beg = rp[d] - deg;
    int j = q;

    for (; j + 12 < deg; j += 16) {
        const int s0 = col[beg + j];
        const int s1 = col[beg + j + 4];
        const int s2 = col[beg + j + 8];
        const int s3 = col[beg + j + 12];
        const u32x2 w0 = *(const u32x2*)(m + (size_t)s0 * FD + c0);
        const u32x2 w1 = *(const u32x2*)(m + (size_t)s1 * FD + c0);
        const u32x2 w2 = *(const u32x2*)(m + (size_t)s2 * FD + c0);
        const u32x2 w3 = *(const u32x2*)(m + (size_t)s3 * FD + c0);
        float v0[8], v1[8], v2[8], v3[8];
        UNPK8(w0, v0) UNPK8(w1, v1) UNPK8(w2, v2) UNPK8(w3, v3)
        if (MODE == 0) {
            #pragma unroll
            for (int i = 0; i < 8; ++i)
                acc[i] += (v0[i] + v1[i]) + (v2[i] + v3[i]);
        } else {
            float e0 = __expf(lrelu(asrc[s0] + ad));
            float e1 = __expf(lrelu(asrc[s1] + ad));
            float e2 = __expf(lrelu(asrc[s2] + ad));
            float e3 = __expf(lrelu(asrc[s3] + ad));
            #pragma unroll
            for (int i = 0; i < 8; ++i) {
                acc[i] = fmaf(e0, v0[i], acc[i]);
                acc[i] = fmaf(e1, v1[i], acc[i]);
                acc[i] = fmaf(e2, v2[i], acc[i]);
                acc[i] = fmaf(e3, v3[i], acc[i]);
            }
            denom += e0 + e1 + e2 + e3;
        }
    }
    for (; j < deg; j += 4) {
        const int s = col[beg + j];
        const u32x2 w = *(const u32x2*)(m + (size_t)s * FD + c0);
        float v[8];
        UNPK8(w, v)
        if (MODE == 0) {
            #pragma unroll
            for (int i = 0; i < 8; ++i) acc[i] += v[i];
        } else {
            float e0 = __expf(lrelu(asrc[s] + ad));
            #pragma unroll
            for (int i = 0; i < 8; ++i) acc[i] = fmaf(e0, v[i], acc[i]);
            denom += e0;
        }
    }
    #undef UNPK8

    #pragma unroll
    for (int i = 0; i < 8; ++i) {
        acc[i] += __shfl_xor(acc[i], 16);
        acc[i] += __shfl_xor(acc[i], 32);
    }
    if (MODE == 1) {
        denom += __shfl_xor(denom, 16);
        denom += __shfl_xor(denom, 32);
    }

    if (q == 0) {
        float o[8];
        if (MODE == 0) {
            const float dd = dinv[d];
            #pragma unroll
            for (int i = 0; i < 8; ++i) o[i] = fmaxf(fmaf(dd, acc[i], bias[c0 + i]), 0.f);
        } else {
            float inv = 1.0f / denom;
            #pragma unroll
            for (int i = 0; i < 8; ++i) o[i] = acc[i] * inv;
        }
        u16x8 ou;
        #pragma unroll
        for (int i = 0; i < 8; ++i) ou[i] = f2bf(o[i]);
        *(u16x8*)(out + (size_t)d * FD + c0) = ou;
    }
}

// ---------- mean over nodes + final scale/bias (coalesced, last-block) ----------
__global__ __launch_bounds__(256) void k_reduce(const unsigned short* __restrict__ val,
                                                float* out, const float* __restrict__ bg,
                                                int* counters, int n, float invn) {
    const int rg = threadIdx.x >> 4;
    const int cg = threadIdx.x & 15;
    const int c0 = cg * 8;
    float acc[8];
    #pragma unroll
    for (int i = 0; i < 8; ++i) acc[i] = 0.f;

    for (int i = blockIdx.x * 16 + rg; i < n; i += gridDim.x * 16) {
        u16x8 u = *(const u16x8*)(val + (size_t)i * FD + c0);
        #pragma unroll
        for (int k = 0; k < 8; ++k) acc[k] += bf2f(u[k]);
    }

    __shared__ float lds[16][129];
    #pragma unroll
    for (int k = 0; k < 8; ++k) lds[rg][c0 + k] = acc[k];
    __syncthreads();
    if (threadIdx.x < 128) {
        float s = 0.f;
        #pragma unroll
        for (int k = 0; k < 16; ++k) s += lds[k][threadIdx.x];
        atomicAdd(&out[threadIdx.x], s);
    }
    __syncthreads();
    __threadfence();
    __shared__ int lastflag;
    if (threadIdx.x == 0) {
        int old = atomicAdd(&counters[0], 1);
        lastflag = (old == (int)gridDim.x - 1);
    }
    __syncthreads();
    if (lastflag) {
        __threadfence();
        if (threadIdx.x < 128) {
            float v = atomicAdd(&out[threadIdx.x], 0.0f);
            out[threadIdx.x] = v * invn + bg[threadIdx.x];
        }
    }
}

// ---------- launch ----------
extern "C" void kernel_launch(void* const* d_in, const int* in_sizes, int n_in,
                              void* d_out, int out_size, void* d_ws, size_t ws_size,
                              hipStream_t stream) {
    const float* x      = (const float*)d_in[0];
    const int*   ei     = (const int*)d_in[1];
    const float* W_emb  = (const float*)d_in[2];
    const float* b_emb  = (const float*)d_in[3];
    const float* W1     = (const float*)d_in[4];
    const float* b1     = (const float*)d_in[5];
    const float* W2     = (const float*)d_in[6];
    const float* b2     = (const float*)d_in[7];
    const float* Wg     = (const float*)d_in[8];
    const float* a_src  = (const float*)d_in[9];
    const float* a_dst  = (const float*)d_in[10];
    const float* bg     = (const float*)d_in[11];

    const int n = in_sizes[0] / FD;   // 50000
    const int e = in_sizes[1] / 2;    // 800000
    const int* src = ei;
    const int* dst = ei + e;

    // layout: 4-byte-aligned regions first, u16 col, u8 fp8 buffer last
    unsigned short* bufB = (unsigned short*)d_ws;           // n*128 bf16 (h)
    unsigned short* Wt4  = bufB + (size_t)n * FD;           // 3 * 128*128 bf16
    float* dinv  = (float*)(Wt4 + 3 * FD * FD);
    float* asrc  = dinv + n;
    float* adst  = asrc + n;
    int*   cnt   = (int*)(adst + n);
    int*   rp    = cnt + n;
    int*   pk    = rp + n;            // e
    int*   ghist = pk + e;            // 65536
    int*   Sg    = ghist + NB * 256;  // 65536
    int*   bsum  = Sg + NB * 256;     // 256
    int*   counters = bsum + 256;     // 2
    unsigned short* col = (unsigned short*)(counters + 2);  // e u16
    unsigned char*  bufM = (unsigned char*)(col + e);       // n*128 fp8

    const dim3 B(256);
    const int chunk  = (e + NB - 1) / NB;
    const int gnode4 = (n + 3) / 4;
    const int gb128  = (n + 127) / 128;   // 391

    // 1) mega0: emb-GEMM | bhist | wcvt | zero
    k_mega0<<<gb128 + 256 + 96 + 1, 512, 0, stream>>>(x, W_emb, b_emb, bufB,
                                                      dst, ghist, e, chunk,
                                                      W1, W2, Wg, Wt4,
                                                      (float*)d_out, counters, n, gb128);
    // 2-4) sort
    k_scan1<<<256, B, 0, stream>>>(ghist, Sg, bsum, counters, NB * 256);
    k_bscatter<<<NB, B, 0, stream>>>(dst, src, Sg, ghist, bsum, pk, e, chunk);
    k_bfinal<<<256, B, 0, stream>>>(pk, Sg, ghist, bsum, cnt, rp, dinv, col, e, n);

    // 5-6) GCN layer 1: m' = dinv * (h0 @ W1)  (fp8); h1 = relu(dinv*sum + b1)
    k_gemm<false, true><<<gb128, 512, 0, stream>>>(bufB, Wt4 + 0 * FD * FD, bufM,
                                                   nullptr, nullptr, nullptr, nullptr, dinv, n);
    k_gather<0><<<gnode4, B, 0, stream>>>(bufM, col, rp, cnt, dinv, b1,
                                          nullptr, nullptr, bufB, n);
    // 7-8) GCN layer 2
    k_gemm<false, true><<<gb128, 512, 0, stream>>>(bufB, Wt4 + 1 * FD * FD, bufM,
                                                   nullptr, nullptr, nullptr, nullptr, dinv, n);
    k_gather<0><<<gnode4, B, 0, stream>>>(bufM, col, rp, cnt, dinv, b2,
                                          nullptr, nullptr, bufB, n);
    // 9-10) GAT
    k_gemm<true, false><<<gb128, 512, 0, stream>>>(bufB, Wt4 + 2 * FD * FD, bufM,
                                                   a_src, a_dst, asrc, adst, nullptr, n);
    k_gather<1><<<gnode4, B, 0, stream>>>(bufM, col, rp, cnt, nullptr, nullptr,
                                          asrc, adst, bufB, n);
    // 11) mean + final
    k_reduce<<<384, B, 0, stream>>>(bufB, (float*)d_out, bg, counters, n, 1.0f / n);
}

// Round 15
// 213.237 us; speedup vs baseline: 1.0749x; 1.0144x over previous
//
#include <hip/hip_runtime.h>

#define FD 128  // feature dim (H = O = 128)
#define NB 256  // sort buckets / hist blocks

typedef __attribute__((ext_vector_type(8))) short bf16x8;
typedef __attribute__((ext_vector_type(8))) unsigned short u16x8;
typedef __attribute__((ext_vector_type(4))) float f32x4;
typedef __attribute__((ext_vector_type(2))) float f32x2;
typedef __attribute__((ext_vector_type(2))) unsigned int u32x2;

__device__ __forceinline__ float lrelu(float x) { return x > 0.f ? x : 0.2f * x; }

__device__ __forceinline__ unsigned short f2bf(float f) {
    unsigned int u = __float_as_uint(f);
    u = (u + 0x7FFFu + ((u >> 16) & 1u)) >> 16;
    return (unsigned short)u;
}
__device__ __forceinline__ float bf2f(unsigned short h) {
    return __uint_as_float((unsigned int)h << 16);
}
// fp8 e4m3 via gfx950 HW converts
__device__ __forceinline__ unsigned char f2fp8(float f) {
    return (unsigned char)(__builtin_amdgcn_cvt_pk_fp8_f32(f, f, 0, false) & 0xFF);
}

// unpack 8 fp8 (u32x2) -> 4 f32x2
#define UNPK(w, v)                                              \
    v[0] = __builtin_amdgcn_cvt_pk_f32_fp8((w)[0], false);      \
    v[1] = __builtin_amdgcn_cvt_pk_f32_fp8((w)[0], true);       \
    v[2] = __builtin_amdgcn_cvt_pk_f32_fp8((w)[1], false);      \
    v[3] = __builtin_amdgcn_cvt_pk_f32_fp8((w)[1], true);

// ---------- MFMA GEMM body: C[n,128] = act(A @ W (+ b)) [* dinv] ----------
// C8: fp8 e4m3 output (feeds gathers); else bf16.
// SCALE: multiply output row by dinv[row] (GCN source-norm folded into GEMM).
template <bool BIAS_RELU, bool AV, bool AFP32, bool WF32, bool SCALE, bool C8>
__device__ __forceinline__ void gemm_body(const void* __restrict__ Av,
                                          const void* __restrict__ Wsrc,
                                          const float* __restrict__ b,
                                          void* __restrict__ C,
                                          const float* __restrict__ av_s,
                                          const float* __restrict__ av_d,
                                          float* asrc, float* adst,
                                          const float* __restrict__ dinv, int n, int bid) {
    __shared__ unsigned short Wt[FD][136];
    if (WF32) {
        const float* W = (const float*)Wsrc;
        for (int idx = threadIdx.x; idx < FD * FD; idx += 512) {
            int k = idx >> 7, j = idx & 127;
            Wt[j][k] = f2bf(W[idx]);
        }
    } else {
        const unsigned short* Wtg = (const unsigned short*)Wsrc;
        #pragma unroll
        for (int it = 0; it < 4; ++it) {
            int idx = (it * 512 + threadIdx.x) * 8;
            int j = idx >> 7, k = idx & 127;
            *(u16x8*)&Wt[j][k] = *(const u16x8*)&Wtg[idx];
        }
    }
    __syncthreads();

    const int wid = threadIdx.x >> 6;
    const int lane = threadIdx.x & 63;
    const int lm = lane & 15;
    const int lh = lane >> 4;
    const int row0 = bid * 128 + wid * 16;

    const int arow = min(row0 + lm, n - 1);
    bf16x8 a0, a1, a2, a3;
    if (AFP32) {
        const float* Ar = (const float*)Av + (size_t)arow * FD + lh * 8;
        #pragma unroll
        for (int kk = 0; kk < 4; ++kk) {
            float4 lo = *(const float4*)(Ar + kk * 32);
            float4 hi = *(const float4*)(Ar + kk * 32 + 4);
            bf16x8 a;
            a[0] = (short)f2bf(lo.x); a[1] = (short)f2bf(lo.y);
            a[2] = (short)f2bf(lo.z); a[3] = (short)f2bf(lo.w);
            a[4] = (short)f2bf(hi.x); a[5] = (short)f2bf(hi.y);
            a[6] = (short)f2bf(hi.z); a[7] = (short)f2bf(hi.w);
            if (kk == 0) a0 = a; else if (kk == 1) a1 = a; else if (kk == 2) a2 = a; else a3 = a;
        }
    } else {
        const unsigned short* Ar = (const unsigned short*)Av + (size_t)arow * FD + lh * 8;
        a0 = *(const bf16x8*)(Ar);
        a1 = *(const bf16x8*)(Ar + 32);
        a2 = *(const bf16x8*)(Ar + 64);
        a3 = *(const bf16x8*)(Ar + 96);
    }

    f32x4 acc[8];
    #pragma unroll
    for (int nt = 0; nt < 8; ++nt) acc[nt] = (f32x4){0.f, 0.f, 0.f, 0.f};

    #pragma unroll
    for (int nt = 0; nt < 8; ++nt) {
        const unsigned short* wp = &Wt[nt * 16 + lm][lh * 8];
        bf16x8 b0 = *(const bf16x8*)(wp);
        bf16x8 b1 = *(const bf16x8*)(wp + 32);
        bf16x8 b2 = *(const bf16x8*)(wp + 64);
        bf16x8 b3 = *(const bf16x8*)(wp + 96);
        acc[nt] = __builtin_amdgcn_mfma_f32_16x16x32_bf16(a0, b0, acc[nt], 0, 0, 0);
        acc[nt] = __builtin_amdgcn_mfma_f32_16x16x32_bf16(a1, b1, acc[nt], 0, 0, 0);
        acc[nt] = __builtin_amdgcn_mfma_f32_16x16x32_bf16(a2, b2, acc[nt], 0, 0, 0);
        acc[nt] = __builtin_amdgcn_mfma_f32_16x16x32_bf16(a3, b3, acc[nt], 0, 0, 0);
    }

    float dv[4];
    if (SCALE) {
        #pragma unroll
        for (int r = 0; r < 4; ++r) {
            const int row = row0 + 4 * lh + r;
            dv[r] = dinv[min(row, n - 1)];
        }
    }

    #pragma unroll
    for (int nt = 0; nt < 8; ++nt) {
        const int c = nt * 16 + lm;
        float bv = 0.f;
        if (BIAS_RELU) bv = b[c];
        #pragma unroll
        for (int r = 0; r < 4; ++r) {
            const int row = row0 + 4 * lh + r;
            float v = acc[nt][r];
            if (BIAS_RELU) v = fmaxf(v + bv, 0.f);
            if (SCALE) v *= dv[r];
            if (row < n) {
                if (C8) ((unsigned char*)C)[(size_t)row * FD + c] = f2fp8(v);
                else    ((unsigned short*)C)[(size_t)row * FD + c] = f2bf(v);
            }
        }
    }

    if (AV) {
        float asv[8], adv[8];
        #pragma unroll
        for (int nt = 0; nt < 8; ++nt) {
            asv[nt] = av_s[nt * 16 + lm];
            adv[nt] = av_d[nt * 16 + lm];
        }
        #pragma unroll
        for (int r = 0; r < 4; ++r) {
            float ps = 0.f, pd = 0.f;
            #pragma unroll
            for (int nt = 0; nt < 8; ++nt) {
                ps = fmaf(acc[nt][r], asv[nt], ps);
                pd = fmaf(acc[nt][r], adv[nt], pd);
            }
            #pragma unroll
            for (int m = 1; m < 16; m <<= 1) {
                ps += __shfl_xor(ps, m);
                pd += __shfl_xor(pd, m);
            }
            const int row = row0 + 4 * lh + r;
            if (lm == 0 && row < n) { asrc[row] = ps; adst[row] = pd; }
        }
    }
}

// ---------- mega kernel 0: emb-GEMM | bucket-hist | W cvt | zero ----------
__global__ __launch_bounds__(512) void k_mega0(const float* __restrict__ x,
                                               const float* __restrict__ W_emb,
                                               const float* __restrict__ b_emb,
                                               unsigned short* __restrict__ h0,
                                               const int* __restrict__ dst, int* ghist,
                                               int e, int chunk,
                                               const float* __restrict__ W1,
                                               const float* __restrict__ W2,
                                               const float* __restrict__ Wg,
                                               unsigned short* __restrict__ Wt4,
                                               float* out, int* counters, int n, int gb) {
    const int bx = blockIdx.x;
    if (bx < gb) {
        gemm_body<true, false, true, true, false, false>(x, W_emb, b_emb, h0,
                                                         nullptr, nullptr, nullptr, nullptr,
                                                         nullptr, n, bx);
        return;
    }
    if (bx < gb + 256) {
        __shared__ int h[256];
        if (threadIdx.x < 256) h[threadIdx.x] = 0;
        __syncthreads();
        const int blk = bx - gb;
        const int i0 = blk * chunk;
        const int i1 = min(i0 + chunk, e);
        for (int i = i0 + threadIdx.x; i < i1; i += 512)
            atomicAdd(&h[dst[i] >> 8], 1);
        __syncthreads();
        if (threadIdx.x < 256) ghist[threadIdx.x * NB + blk] = h[threadIdx.x];
        return;
    }
    if (bx < gb + 256 + 96) {
        const int elem = (bx - gb - 256) * 512 + threadIdx.x;   // [0, 49152)
        const int sel = elem >> 14;
        const int within = elem & 16383;
        const int k = within >> 7, j = within & 127;
        const float* Ws = (sel == 0) ? W1 : (sel == 1) ? W2 : Wg;
        Wt4[sel * FD * FD + j * FD + k] = f2bf(Ws[within]);
        return;
    }
    if (threadIdx.x < 128) out[threadIdx.x] = 0.f;
    if (threadIdx.x == 128) counters[0] = 0;
    if (threadIdx.x == 129) counters[1] = 0;
}

// ---------- standalone GEMM (fp8 out) ----------
template <bool AV, bool SCALE>
__global__ __launch_bounds__(512) void k_gemm(const unsigned short* __restrict__ A,
                                              const unsigned short* __restrict__ Wtg,
                                              unsigned char* __restrict__ C,
                                              const float* __restrict__ av_s,
                                              const float* __restrict__ av_d,
                                              float* asrc, float* adst,
                                              const float* __restrict__ dinv, int n) {
    gemm_body<false, AV, false, false, SCALE, true>(A, Wtg, nullptr, C, av_s, av_d,
                                                    asrc, adst, dinv, n, blockIdx.x);
}

// ---------- scan (scan2 folded via last-block) ----------
__global__ __launch_bounds__(256) void k_scan1(const int* __restrict__ v, int* S,
                                               int* bsum, int* counters, int n) {
    __shared__ int lds[256];
    int i = blockIdx.x * 256 + threadIdx.x;
    int x = (i < n) ? v[i] : 0;
    lds[threadIdx.x] = x;
    __syncthreads();
    for (int off = 1; off < 256; off <<= 1) {
        int t = (threadIdx.x >= off) ? lds[threadIdx.x - off] : 0;
        __syncthreads();
        lds[threadIdx.x] += t;
        __syncthreads();
    }
    if (i < n) S[i] = lds[threadIdx.x];
    if (threadIdx.x == 255) bsum[blockIdx.x] = lds[255];
    __threadfence();
    __shared__ int lastflag;
    if (threadIdx.x == 0) {
        int old = atomicAdd(&counters[1], 1);
        lastflag = (old == (int)gridDim.x - 1);
    }
    __syncthreads();
    if (!lastflag) return;
    int bv = atomicAdd(&bsum[threadIdx.x], 0);
    lds[threadIdx.x] = bv;
    __syncthreads();
    for (int off = 1; off < 256; off <<= 1) {
        int t = (threadIdx.x >= off) ? lds[threadIdx.x - off] : 0;
        __syncthreads();
        lds[threadIdx.x] += t;
        __syncthreads();
    }
    bsum[threadIdx.x] = lds[threadIdx.x];
}

// ---------- bucket scatter ----------
__global__ __launch_bounds__(256) void k_bscatter(const int* __restrict__ dst,
                                                  const int* __restrict__ src,
                                                  const int* __restrict__ S,
                                                  const int* __restrict__ gh,
                                                  const int* __restrict__ bsum,
                                                  int* pk, int e, int chunk) {
    __shared__ int cur[256];
    const int t = threadIdx.x;
    const int idx = t * NB + blockIdx.x;
    cur[t] = S[idx] - gh[idx] + ((t > 0) ? bsum[t - 1] : 0);
    __syncthreads();
    const int i0 = blockIdx.x * chunk;
    const int i1 = min(i0 + chunk, e);
    for (int i = i0 + t; i < i1; i += 256) {
        int d = dst[i];
        int s = src[i];
        int pos = atomicAdd(&cur[d >> 8], 1);
        pk[pos] = (d << 16) | s;
    }
}

// ---------- per-bucket finalize: cnt, rp (segment END), dinv, col (u16) ----------
__global__ __launch_bounds__(256) void k_bfinal(const int* __restrict__ pk,
                                                const int* __restrict__ S,
                                                const int* __restrict__ gh,
                                                const int* __restrict__ bsum,
                                                int* cnt, int* rp, float* dinv,
                                                unsigned short* col, int e, int n) {
    __shared__ int cl[256];
    __shared__ int sc[256];
    const int b = blockIdx.x;
    const int i0 = b * NB;
    const int base = S[i0] - gh[i0] + ((b > 0) ? bsum[b - 1] : 0);
    int end;
    if (b < 255) {
        const int i1 = (b + 1) * NB;
        end = S[i1] - gh[i1] + bsum[b];
    } else {
        end = e;
    }
    cl[threadIdx.x] = 0;
    __syncthreads();
    for (int j = base + threadIdx.x; j < end; j += 256)
        atomicAdd(&cl[(pk[j] >> 16) & 255], 1);
    __syncthreads();
    sc[threadIdx.x] = cl[threadIdx.x];
    __syncthreads();
    for (int off = 1; off < 256; off <<= 1) {
        int t = (threadIdx.x >= off) ? sc[threadIdx.x - off] : 0;
        __syncthreads();
        sc[threadIdx.x] += t;
        __syncthreads();
    }
    const int c = cl[threadIdx.x];
    const int incl = sc[threadIdx.x];
    const int d = b * 256 + threadIdx.x;
    if (d < n) {
        cnt[d] = c;
        rp[d] = base + incl;
        dinv[d] = rsqrtf((float)c + 1.0f);
    }
    __syncthreads();
    sc[threadIdx.x] = base + incl - c;
    __syncthreads();
    for (int j = base + threadIdx.x; j < end; j += 256) {
        int p = pk[j];
        int pos = atomicAdd(&sc[(p >> 16) & 255], 1);
        col[pos] = (unsigned short)(p & 0xFFFF);
    }
}

// ---------- fused gather over fp8 rows, packed f32x2 math ----------
// MODE 0 (GCN, dinv folded into m): out(bf16)[d] = relu( dinv[d]*(m'[d]+sum m'[s]) + bias )
// MODE 1 (GAT): out(fp8)[d] = ( sum w_sd g[s] ) / ( sum w_sd ), w = __expf(lrelu(asrc[s]+adst[d]))
template <int MODE>
__global__ __launch_bounds__(256) void k_gather(const unsigned char* __restrict__ m,
                                                const unsigned short* __restrict__ col,
                                                const int* __restrict__ rp,
                                                const int* __restrict__ cnt,
                                                const float* __restrict__ dinv,
                                                const float* __restrict__ bias,
                                                const float* __restrict__ asrc,
                                                const float* __restrict__ adst,
                                                void* __restrict__ outv, int n) {
    const int wave = threadIdx.x >> 6;
    const int lane = threadIdx.x & 63;
    const int q = lane >> 4;
    const int l16 = lane & 15;
    const int d = blockIdx.x * 4 + wave;
    if (d >= n) return;
    const int c0 = l16 * 8;   // byte offset == col offset (1 B/col)

    const float ad = (MODE == 1) ? adst[d] : 0.f;

    f32x2 acc[4];
    #pragma unroll
    for (int i = 0; i < 4; ++i) acc[i] = (f32x2){0.f, 0.f};
    float denom = 0.f;

    if (q == 0) {  // self term
        u32x2 w = *(const u32x2*)(m + (size_t)d * FD + c0);
        f32x2 v[4];
        UNPK(w, v)
        if (MODE == 0) {
            #pragma unroll
            for (int i = 0; i < 4; ++i) acc[i] = v[i];
        } else {
            float ww = __expf(lrelu(asrc[d] + ad));
            f32x2 w2 = {ww, ww};
            #pragma unroll
            for (int i = 0; i < 4; ++i) acc[i] = w2 * v[i];
            denom = ww;
        }
    }

    const int deg = cnt[d];
    const int beg = rp[d] - deg;
    int j = q;

    for (; j + 12 < deg; j += 16) {
        const int s0 = col[beg + j];
        const int s1 = col[beg + j + 4];
        const int s2 = col[beg + j + 8];
        const int s3 = col[beg + j + 12];
        const u32x2 w0 = *(const u32x2*)(m + (size_t)s0 * FD + c0);
        const u32x2 w1 = *(const u32x2*)(m + (size_t)s1 * FD + c0);
        const u32x2 w2 = *(const u32x2*)(m + (size_t)s2 * FD + c0);
        const u32x2 w3 = *(const u32x2*)(m + (size_t)s3 * FD + c0);
        f32x2 v0[4], v1[4], v2[4], v3[4];
        UNPK(w0, v0) UNPK(w1, v1) UNPK(w2, v2) UNPK(w3, v3)
        if (MODE == 0) {
            #pragma unroll
            for (int i = 0; i < 4; ++i)
                acc[i] += (v0[i] + v1[i]) + (v2[i] + v3[i]);
        } else {
            float e0 = __expf(lrelu(asrc[s0] + ad));
            float e1 = __expf(lrelu(asrc[s1] + ad));
            float e2 = __expf(lrelu(asrc[s2] + ad));
            float e3 = __expf(lrelu(asrc[s3] + ad));
            f32x2 e02 = {e0, e0}, e12 = {e1, e1}, e22 = {e2, e2}, e32 = {e3, e3};
            #pragma unroll
            for (int i = 0; i < 4; ++i) {
                acc[i] = __builtin_elementwise_fma(e02, v0[i], acc[i]);
                acc[i] = __builtin_elementwise_fma(e12, v1[i], acc[i]);
                acc[i] = __builtin_elementwise_fma(e22, v2[i], acc[i]);
                acc[i] = __builtin_elementwise_fma(e32, v3[i], acc[i]);
            }
            denom += e0 + e1 + e2 + e3;
        }
    }
    for (; j < deg; j += 4) {
        const int s = col[beg + j];
        const u32x2 w = *(const u32x2*)(m + (size_t)s * FD + c0);
        f32x2 v[4];
        UNPK(w, v)
        if (MODE == 0) {
            #pragma unroll
            for (int i = 0; i < 4; ++i) acc[i] += v[i];
        } else {
            float e0 = __expf(lrelu(asrc[s] + ad));
            f32x2 e02 = {e0, e0};
            #pragma unroll
            for (int i = 0; i < 4; ++i) acc[i] = __builtin_elementwise_fma(e02, v[i], acc[i]);
            denom += e0;
        }
    }

    #pragma unroll
    for (int i = 0; i < 4; ++i) {
        float a = acc[i][0], b = acc[i][1];
        a += __shfl_xor(a, 16); a += __shfl_xor(a, 32);
        b += __shfl_xor(b, 16); b += __shfl_xor(b, 32);
        acc[i][0] = a; acc[i][1] = b;
    }
    if (MODE == 1) {
        denom += __shfl_xor(denom, 16);
        denom += __shfl_xor(denom, 32);
    }

    if (q == 0) {
        float o[8];
        #pragma unroll
        for (int i = 0; i < 8; ++i) o[i] = acc[i >> 1][i & 1];
        if (MODE == 0) {
            const float dd = dinv[d];
            u16x8 ou;
            #pragma unroll
            for (int i = 0; i < 8; ++i)
                ou[i] = f2bf(fmaxf(fmaf(dd, o[i], bias[c0 + i]), 0.f));
            *(u16x8*)((unsigned short*)outv + (size_t)d * FD + c0) = ou;
        } else {
            float inv = 1.0f / denom;
            #pragma unroll
            for (int i = 0; i < 8; ++i) o[i] *= inv;
            unsigned int lo = __builtin_amdgcn_cvt_pk_fp8_f32(o[0], o[1], 0, false);
            lo = __builtin_amdgcn_cvt_pk_fp8_f32(o[2], o[3], lo, true);
            unsigned int hi = __builtin_amdgcn_cvt_pk_fp8_f32(o[4], o[5], 0, false);
            hi = __builtin_amdgcn_cvt_pk_fp8_f32(o[6], o[7], hi, true);
            u32x2 ow = {lo, hi};
            *(u32x2*)((unsigned char*)outv + (size_t)d * FD + c0) = ow;
        }
    }
}

// ---------- mean over fp8 node outputs + final scale/bias (last-block) ----------
__global__ __launch_bounds__(256) void k_reduce(const unsigned char* __restrict__ val,
                                                float* out, const float* __restrict__ bg,
                                                int* counters, int n, float invn) {
    const int rg = threadIdx.x >> 4;
    const int cg = threadIdx.x & 15;
    const int c0 = cg * 8;
    f32x2 acc[4];
    #pragma unroll
    for (int i = 0; i < 4; ++i) acc[i] = (f32x2){0.f, 0.f};

    for (int i = blockIdx.x * 16 + rg; i < n; i += gridDim.x * 16) {
        u32x2 w = *(const u32x2*)(val + (size_t)i * FD + c0);
        f32x2 v[4];
        UNPK(w, v)
        #pragma unroll
        for (int k = 0; k < 4; ++k) acc[k] += v[k];
    }

    __shared__ float lds[16][129];
    #pragma unroll
    for (int k = 0; k < 4; ++k) {
        lds[rg][c0 + 2 * k] = acc[k][0];
        lds[rg][c0 + 2 * k + 1] = acc[k][1];
    }
    __syncthreads();
    if (threadIdx.x < 128) {
        float s = 0.f;
        #pragma unroll
        for (int k = 0; k < 16; ++k) s += lds[k][threadIdx.x];
        atomicAdd(&out[threadIdx.x], s);
    }
    __syncthreads();
    __threadfence();
    __shared__ int lastflag;
    if (threadIdx.x == 0) {
        int old = atomicAdd(&counters[0], 1);
        lastflag = (old == (int)gridDim.x - 1);
    }
    __syncthreads();
    if (lastflag) {
        __threadfence();
        if (threadIdx.x < 128) {
            float v = atomicAdd(&out[threadIdx.x], 0.0f);
            out[threadIdx.x] = v * invn + bg[threadIdx.x];
        }
    }
}

// ---------- launch ----------
extern "C" void kernel_launch(void* const* d_in, const int* in_sizes, int n_in,
                              void* d_out, int out_size, void* d_ws, size_t ws_size,
                              hipStream_t stream) {
    const float* x      = (const float*)d_in[0];
    const int*   ei     = (const int*)d_in[1];
    const float* W_emb  = (const float*)d_in[2];
    const float* b_emb  = (const float*)d_in[3];
    const float* W1     = (const float*)d_in[4];
    const float* b1     = (const float*)d_in[5];
    const float* W2     = (const float*)d_in[6];
    const float* b2     = (const float*)d_in[7];
    const float* Wg     = (const float*)d_in[8];
    const float* a_src  = (const float*)d_in[9];
    const float* a_dst  = (const float*)d_in[10];
    const float* bg     = (const float*)d_in[11];

    const int n = in_sizes[0] / FD;   // 50000
    const int e = in_sizes[1] / 2;    // 800000
    const int* src = ei;
    const int* dst = ei + e;

    unsigned short* bufB = (unsigned short*)d_ws;           // n*128 bf16 (h) / fp8 GAT out
    unsigned short* Wt4  = bufB + (size_t)n * FD;           // 3 * 128*128 bf16
    float* dinv  = (float*)(Wt4 + 3 * FD * FD);
    float* asrc  = dinv + n;
    float* adst  = asrc + n;
    int*   cnt   = (int*)(adst + n);
    int*   rp    = cnt + n;
    int*   pk    = rp + n;            // e
    int*   ghist = pk + e;            // 65536
    int*   Sg    = ghist + NB * 256;  // 65536
    int*   bsum  = Sg + NB * 256;     // 256
    int*   counters = bsum + 256;     // 2
    unsigned short* col = (unsigned short*)(counters + 2);  // e u16
    unsigned char*  bufM = (unsigned char*)(col + e);       // n*128 fp8

    const dim3 B(256);
    const int chunk  = (e + NB - 1) / NB;
    const int gnode4 = (n + 3) / 4;
    const int gb128  = (n + 127) / 128;   // 391

    // 1) mega0: emb-GEMM | bhist | wcvt | zero
    k_mega0<<<gb128 + 256 + 96 + 1, 512, 0, stream>>>(x, W_emb, b_emb, bufB,
                                                      dst, ghist, e, chunk,
                                                      W1, W2, Wg, Wt4,
                                                      (float*)d_out, counters, n, gb128);
    // 2-4) sort
    k_scan1<<<256, B, 0, stream>>>(ghist, Sg, bsum, counters, NB * 256);
    k_bscatter<<<NB, B, 0, stream>>>(dst, src, Sg, ghist, bsum, pk, e, chunk);
    k_bfinal<<<256, B, 0, stream>>>(pk, Sg, ghist, bsum, cnt, rp, dinv, col, e, n);

    // 5-6) GCN layer 1: m' = dinv * (h0 @ W1)  (fp8); h1 = relu(dinv*sum + b1) (bf16)
    k_gemm<false, true><<<gb128, 512, 0, stream>>>(bufB, Wt4 + 0 * FD * FD, bufM,
                                                   nullptr, nullptr, nullptr, nullptr, dinv, n);
    k_gather<0><<<gnode4, B, 0, stream>>>(bufM, col, rp, cnt, dinv, b1,
                                          nullptr, nullptr, bufB, n);
    // 7-8) GCN layer 2
    k_gemm<false, true><<<gb128, 512, 0, stream>>>(bufB, Wt4 + 1 * FD * FD, bufM,
                                                   nullptr, nullptr, nullptr, nullptr, dinv, n);
    k_gather<0><<<gnode4, B, 0, stream>>>(bufM, col, rp, cnt, dinv, b2,
                                          nullptr, nullptr, bufB, n);
    // 9-10) GAT: g (fp8) -> bufM; gather writes fp8 node outputs -> bufB
    k_gemm<true, false><<<gb128, 512, 0, stream>>>(bufB, Wt4 + 2 * FD * FD, bufM,
                                                   a_src, a_dst, asrc, adst, nullptr, n);
    k_gather<1><<<gnode4, B, 0, stream>>>(bufM, col, rp, cnt, nullptr, nullptr,
                                          asrc, adst, bufB, n);
    // 11) mean + final (reads fp8)
    k_reduce<<<384, B, 0, stream>>>((const unsigned char*)bufB, (float*)d_out, bg,
                                    counters, n, 1.0f / n);
}

// Round 16
// 212.294 us; speedup vs baseline: 1.0797x; 1.0044x over previous
//
#include <hip/hip_runtime.h>

#define FD 128  // feature dim (H = O = 128)
#define NB 256  // sort buckets / hist blocks

typedef __attribute__((ext_vector_type(8))) short bf16x8;
typedef __attribute__((ext_vector_type(8))) unsigned short u16x8;
typedef __attribute__((ext_vector_type(4))) float f32x4;
typedef __attribute__((ext_vector_type(2))) float f32x2;
typedef __attribute__((ext_vector_type(2))) unsigned int u32x2;

__device__ __forceinline__ float lrelu(float x) { return x > 0.f ? x : 0.2f * x; }

__device__ __forceinline__ unsigned short f2bf(float f) {
    unsigned int u = __float_as_uint(f);
    u = (u + 0x7FFFu + ((u >> 16) & 1u)) >> 16;
    return (unsigned short)u;
}
__device__ __forceinline__ float bf2f(unsigned short h) {
    return __uint_as_float((unsigned int)h << 16);
}
// fp8 e4m3 via gfx950 HW converts
__device__ __forceinline__ unsigned char f2fp8(float f) {
    return (unsigned char)(__builtin_amdgcn_cvt_pk_fp8_f32(f, f, 0, false) & 0xFF);
}

// unpack 8 fp8 (u32x2) -> 4 f32x2
#define UNPK(w, v)                                              \
    v[0] = __builtin_amdgcn_cvt_pk_f32_fp8((w)[0], false);      \
    v[1] = __builtin_amdgcn_cvt_pk_f32_fp8((w)[0], true);       \
    v[2] = __builtin_amdgcn_cvt_pk_f32_fp8((w)[1], false);      \
    v[3] = __builtin_amdgcn_cvt_pk_f32_fp8((w)[1], true);

// ---------- MFMA GEMM body: C[n,128] = act(A @ W (+ b)) [* dinv] ----------
template <bool BIAS_RELU, bool AV, bool AFP32, bool WF32, bool SCALE, bool C8>
__device__ __forceinline__ void gemm_body(const void* __restrict__ Av,
                                          const void* __restrict__ Wsrc,
                                          const float* __restrict__ b,
                                          void* __restrict__ C,
                                          const float* __restrict__ av_s,
                                          const float* __restrict__ av_d,
                                          float* asrc, float* adst,
                                          const float* __restrict__ dinv, int n, int bid) {
    __shared__ unsigned short Wt[FD][136];
    if (WF32) {
        const float* W = (const float*)Wsrc;
        for (int idx = threadIdx.x; idx < FD * FD; idx += 512) {
            int k = idx >> 7, j = idx & 127;
            Wt[j][k] = f2bf(W[idx]);
        }
    } else {
        const unsigned short* Wtg = (const unsigned short*)Wsrc;
        #pragma unroll
        for (int it = 0; it < 4; ++it) {
            int idx = (it * 512 + threadIdx.x) * 8;
            int j = idx >> 7, k = idx & 127;
            *(u16x8*)&Wt[j][k] = *(const u16x8*)&Wtg[idx];
        }
    }
    __syncthreads();

    const int wid = threadIdx.x >> 6;
    const int lane = threadIdx.x & 63;
    const int lm = lane & 15;
    const int lh = lane >> 4;
    const int row0 = bid * 128 + wid * 16;

    const int arow = min(row0 + lm, n - 1);
    bf16x8 a0, a1, a2, a3;
    if (AFP32) {
        const float* Ar = (const float*)Av + (size_t)arow * FD + lh * 8;
        #pragma unroll
        for (int kk = 0; kk < 4; ++kk) {
            float4 lo = *(const float4*)(Ar + kk * 32);
            float4 hi = *(const float4*)(Ar + kk * 32 + 4);
            bf16x8 a;
            a[0] = (short)f2bf(lo.x); a[1] = (short)f2bf(lo.y);
            a[2] = (short)f2bf(lo.z); a[3] = (short)f2bf(lo.w);
            a[4] = (short)f2bf(hi.x); a[5] = (short)f2bf(hi.y);
            a[6] = (short)f2bf(hi.z); a[7] = (short)f2bf(hi.w);
            if (kk == 0) a0 = a; else if (kk == 1) a1 = a; else if (kk == 2) a2 = a; else a3 = a;
        }
    } else {
        const unsigned short* Ar = (const unsigned short*)Av + (size_t)arow * FD + lh * 8;
        a0 = *(const bf16x8*)(Ar);
        a1 = *(const bf16x8*)(Ar + 32);
        a2 = *(const bf16x8*)(Ar + 64);
        a3 = *(const bf16x8*)(Ar + 96);
    }

    f32x4 acc[8];
    #pragma unroll
    for (int nt = 0; nt < 8; ++nt) acc[nt] = (f32x4){0.f, 0.f, 0.f, 0.f};

    #pragma unroll
    for (int nt = 0; nt < 8; ++nt) {
        const unsigned short* wp = &Wt[nt * 16 + lm][lh * 8];
        bf16x8 b0 = *(const bf16x8*)(wp);
        bf16x8 b1 = *(const bf16x8*)(wp + 32);
        bf16x8 b2 = *(const bf16x8*)(wp + 64);
        bf16x8 b3 = *(const bf16x8*)(wp + 96);
        acc[nt] = __builtin_amdgcn_mfma_f32_16x16x32_bf16(a0, b0, acc[nt], 0, 0, 0);
        acc[nt] = __builtin_amdgcn_mfma_f32_16x16x32_bf16(a1, b1, acc[nt], 0, 0, 0);
        acc[nt] = __builtin_amdgcn_mfma_f32_16x16x32_bf16(a2, b2, acc[nt], 0, 0, 0);
        acc[nt] = __builtin_amdgcn_mfma_f32_16x16x32_bf16(a3, b3, acc[nt], 0, 0, 0);
    }

    float dv[4];
    if (SCALE) {
        #pragma unroll
        for (int r = 0; r < 4; ++r) {
            const int row = row0 + 4 * lh + r;
            dv[r] = dinv[min(row, n - 1)];
        }
    }

    #pragma unroll
    for (int nt = 0; nt < 8; ++nt) {
        const int c = nt * 16 + lm;
        float bv = 0.f;
        if (BIAS_RELU) bv = b[c];
        #pragma unroll
        for (int r = 0; r < 4; ++r) {
            const int row = row0 + 4 * lh + r;
            float v = acc[nt][r];
            if (BIAS_RELU) v = fmaxf(v + bv, 0.f);
            if (SCALE) v *= dv[r];
            if (row < n) {
                if (C8) ((unsigned char*)C)[(size_t)row * FD + c] = f2fp8(v);
                else    ((unsigned short*)C)[(size_t)row * FD + c] = f2bf(v);
            }
        }
    }

    if (AV) {
        float asv[8], adv[8];
        #pragma unroll
        for (int nt = 0; nt < 8; ++nt) {
            asv[nt] = av_s[nt * 16 + lm];
            adv[nt] = av_d[nt * 16 + lm];
        }
        #pragma unroll
        for (int r = 0; r < 4; ++r) {
            float ps = 0.f, pd = 0.f;
            #pragma unroll
            for (int nt = 0; nt < 8; ++nt) {
                ps = fmaf(acc[nt][r], asv[nt], ps);
                pd = fmaf(acc[nt][r], adv[nt], pd);
            }
            #pragma unroll
            for (int m = 1; m < 16; m <<= 1) {
                ps += __shfl_xor(ps, m);
                pd += __shfl_xor(pd, m);
            }
            const int row = row0 + 4 * lh + r;
            if (lm == 0 && row < n) { asrc[row] = ps; adst[row] = pd; }
        }
    }
}

// ---------- mega kernel 0: emb-GEMM | bucket-hist | W cvt | zero ----------
__global__ __launch_bounds__(512) void k_mega0(const float* __restrict__ x,
                                               const float* __restrict__ W_emb,
                                               const float* __restrict__ b_emb,
                                               unsigned short* __restrict__ h0,
                                               const int* __restrict__ dst, int* ghist,
                                               int e, int chunk,
                                               const float* __restrict__ W1,
                                               const float* __restrict__ W2,
                                               const float* __restrict__ Wg,
                                               unsigned short* __restrict__ Wt4,
                                               float* out, int* counters, int n, int gb) {
    const int bx = blockIdx.x;
    if (bx < gb) {
        gemm_body<true, false, true, true, false, false>(x, W_emb, b_emb, h0,
                                                         nullptr, nullptr, nullptr, nullptr,
                                                         nullptr, n, bx);
        return;
    }
    if (bx < gb + 256) {
        __shared__ int h[256];
        if (threadIdx.x < 256) h[threadIdx.x] = 0;
        __syncthreads();
        const int blk = bx - gb;
        const int i0 = blk * chunk;
        const int i1 = min(i0 + chunk, e);
        for (int i = i0 + threadIdx.x; i < i1; i += 512)
            atomicAdd(&h[dst[i] >> 8], 1);
        __syncthreads();
        if (threadIdx.x < 256) ghist[threadIdx.x * NB + blk] = h[threadIdx.x];
        return;
    }
    if (bx < gb + 256 + 96) {
        const int elem = (bx - gb - 256) * 512 + threadIdx.x;   // [0, 49152)
        const int sel = elem >> 14;
        const int within = elem & 16383;
        const int k = within >> 7, j = within & 127;
        const float* Ws = (sel == 0) ? W1 : (sel == 1) ? W2 : Wg;
        Wt4[sel * FD * FD + j * FD + k] = f2bf(Ws[within]);
        return;
    }
    if (threadIdx.x < 128) out[threadIdx.x] = 0.f;
    if (threadIdx.x == 128) counters[0] = 0;
    if (threadIdx.x == 129) counters[1] = 0;
}

// ---------- standalone GEMM (fp8 out) ----------
template <bool AV, bool SCALE>
__global__ __launch_bounds__(512) void k_gemm(const unsigned short* __restrict__ A,
                                              const unsigned short* __restrict__ Wtg,
                                              unsigned char* __restrict__ C,
                                              const float* __restrict__ av_s,
                                              const float* __restrict__ av_d,
                                              float* asrc, float* adst,
                                              const float* __restrict__ dinv, int n) {
    gemm_body<false, AV, false, false, SCALE, true>(A, Wtg, nullptr, C, av_s, av_d,
                                                    asrc, adst, dinv, n, blockIdx.x);
}

// ---------- scan (scan2 folded via last-block) ----------
__global__ __launch_bounds__(256) void k_scan1(const int* __restrict__ v, int* S,
                                               int* bsum, int* counters, int n) {
    __shared__ int lds[256];
    int i = blockIdx.x * 256 + threadIdx.x;
    int x = (i < n) ? v[i] : 0;
    lds[threadIdx.x] = x;
    __syncthreads();
    for (int off = 1; off < 256; off <<= 1) {
        int t = (threadIdx.x >= off) ? lds[threadIdx.x - off] : 0;
        __syncthreads();
        lds[threadIdx.x] += t;
        __syncthreads();
    }
    if (i < n) S[i] = lds[threadIdx.x];
    if (threadIdx.x == 255) bsum[blockIdx.x] = lds[255];
    __threadfence();
    __shared__ int lastflag;
    if (threadIdx.x == 0) {
        int old = atomicAdd(&counters[1], 1);
        lastflag = (old == (int)gridDim.x - 1);
    }
    __syncthreads();
    if (!lastflag) return;
    int bv = atomicAdd(&bsum[threadIdx.x], 0);
    lds[threadIdx.x] = bv;
    __syncthreads();
    for (int off = 1; off < 256; off <<= 1) {
        int t = (threadIdx.x >= off) ? lds[threadIdx.x - off] : 0;
        __syncthreads();
        lds[threadIdx.x] += t;
        __syncthreads();
    }
    bsum[threadIdx.x] = lds[threadIdx.x];
}

// ---------- bucket scatter ----------
__global__ __launch_bounds__(256) void k_bscatter(const int* __restrict__ dst,
                                                  const int* __restrict__ src,
                                                  const int* __restrict__ S,
                                                  const int* __restrict__ gh,
                                                  const int* __restrict__ bsum,
                                                  int* pk, int e, int chunk) {
    __shared__ int cur[256];
    const int t = threadIdx.x;
    const int idx = t * NB + blockIdx.x;
    cur[t] = S[idx] - gh[idx] + ((t > 0) ? bsum[t - 1] : 0);
    __syncthreads();
    const int i0 = blockIdx.x * chunk;
    const int i1 = min(i0 + chunk, e);
    for (int i = i0 + t; i < i1; i += 256) {
        int d = dst[i];
        int s = src[i];
        int pos = atomicAdd(&cur[d >> 8], 1);
        pk[pos] = (d << 16) | s;
    }
}

// ---------- per-bucket finalize: cnt, rp (segment END), dinv, col (u16) ----------
__global__ __launch_bounds__(256) void k_bfinal(const int* __restrict__ pk,
                                                const int* __restrict__ S,
                                                const int* __restrict__ gh,
                                                const int* __restrict__ bsum,
                                                int* cnt, int* rp, float* dinv,
                                                unsigned short* col, int e, int n) {
    __shared__ int cl[256];
    __shared__ int sc[256];
    const int b = blockIdx.x;
    const int i0 = b * NB;
    const int base = S[i0] - gh[i0] + ((b > 0) ? bsum[b - 1] : 0);
    int end;
    if (b < 255) {
        const int i1 = (b + 1) * NB;
        end = S[i1] - gh[i1] + bsum[b];
    } else {
        end = e;
    }
    cl[threadIdx.x] = 0;
    __syncthreads();
    for (int j = base + threadIdx.x; j < end; j += 256)
        atomicAdd(&cl[(pk[j] >> 16) & 255], 1);
    __syncthreads();
    sc[threadIdx.x] = cl[threadIdx.x];
    __syncthreads();
    for (int off = 1; off < 256; off <<= 1) {
        int t = (threadIdx.x >= off) ? sc[threadIdx.x - off] : 0;
        __syncthreads();
        sc[threadIdx.x] += t;
        __syncthreads();
    }
    const int c = cl[threadIdx.x];
    const int incl = sc[threadIdx.x];
    const int d = b * 256 + threadIdx.x;
    if (d < n) {
        cnt[d] = c;
        rp[d] = base + incl;
        dinv[d] = rsqrtf((float)c + 1.0f);
    }
    __syncthreads();
    sc[threadIdx.x] = base + incl - c;
    __syncthreads();
    for (int j = base + threadIdx.x; j < end; j += 256) {
        int p = pk[j];
        int pos = atomicAdd(&sc[(p >> 16) & 255], 1);
        col[pos] = (unsigned short)(p & 0xFFFF);
    }
}

// ---------- fused gather over fp8 rows, lane-distributed edge weights ----------
// 16-edge batches: lane l owns edge j+(l&15) -> ONE col load + ONE exp per lane
// per batch (was 4 each, 16x redundant exp); quarters fetch their 4 edge
// indices/weights via __shfl from lanes 0-15.
// MODE 0 (GCN, dinv folded into m): out(bf16)[d] = relu( dinv[d]*(m'[d]+sum m'[s]) + bias )
// MODE 1 (GAT): out(fp8)[d] = ( sum w g[s] ) / ( sum w ), w = __expf(lrelu(asrc[s]+adst[d]))
template <int MODE>
__global__ __launch_bounds__(256) void k_gather(const unsigned char* __restrict__ m,
                                                const unsigned short* __restrict__ col,
                                                const int* __restrict__ rp,
                                                const int* __restrict__ cnt,
                                                const float* __restrict__ dinv,
                                                const float* __restrict__ bias,
                                                const float* __restrict__ asrc,
                                                const float* __restrict__ adst,
                                                void* __restrict__ outv, int n) {
    const int wave = threadIdx.x >> 6;
    const int lane = threadIdx.x & 63;
    const int q = lane >> 4;
    const int l16 = lane & 15;
    const int d = blockIdx.x * 4 + wave;
    if (d >= n) return;
    const int c0 = l16 * 8;   // byte offset == col offset (1 B/col)

    const float ad = (MODE == 1) ? adst[d] : 0.f;

    f32x2 acc[4];
    #pragma unroll
    for (int i = 0; i < 4; ++i) acc[i] = (f32x2){0.f, 0.f};
    float denom = 0.f;

    if (q == 0) {  // self term
        u32x2 w = *(const u32x2*)(m + (size_t)d * FD + c0);
        f32x2 v[4];
        UNPK(w, v)
        if (MODE == 0) {
            #pragma unroll
            for (int i = 0; i < 4; ++i) acc[i] = v[i];
        } else {
            float ww = __expf(lrelu(asrc[d] + ad));
            f32x2 w2 = {ww, ww};
            #pragma unroll
            for (int i = 0; i < 4; ++i) acc[i] = w2 * v[i];
            denom = ww;
        }
    }

    const int deg = cnt[d];
    const int beg = rp[d] - deg;
    int j = 0;

    // main: 16 edges/batch; lane owns edge j+l16
    for (; j + 15 < deg; j += 16) {
        const int cidx = col[beg + j + l16];
        float wv = 0.f;
        if (MODE == 1) wv = __expf(lrelu(asrc[cidx] + ad));
        // quarter q handles edges j+4q .. j+4q+3 (src lanes 4q..4q+3)
        const int s0 = __shfl(cidx, 4 * q + 0);
        const int s1 = __shfl(cidx, 4 * q + 1);
        const int s2 = __shfl(cidx, 4 * q + 2);
        const int s3 = __shfl(cidx, 4 * q + 3);
        const u32x2 w0 = *(const u32x2*)(m + (size_t)s0 * FD + c0);
        const u32x2 w1 = *(const u32x2*)(m + (size_t)s1 * FD + c0);
        const u32x2 w2 = *(const u32x2*)(m + (size_t)s2 * FD + c0);
        const u32x2 w3 = *(const u32x2*)(m + (size_t)s3 * FD + c0);
        f32x2 v0[4], v1[4], v2[4], v3[4];
        UNPK(w0, v0) UNPK(w1, v1) UNPK(w2, v2) UNPK(w3, v3)
        if (MODE == 0) {
            #pragma unroll
            for (int i = 0; i < 4; ++i)
                acc[i] += (v0[i] + v1[i]) + (v2[i] + v3[i]);
        } else {
            const float e0 = __shfl(wv, 4 * q + 0);
            const float e1 = __shfl(wv, 4 * q + 1);
            const float e2 = __shfl(wv, 4 * q + 2);
            const float e3 = __shfl(wv, 4 * q + 3);
            f32x2 e02 = {e0, e0}, e12 = {e1, e1}, e22 = {e2, e2}, e32 = {e3, e3};
            #pragma unroll
            for (int i = 0; i < 4; ++i) {
                acc[i] = __builtin_elementwise_fma(e02, v0[i], acc[i]);
                acc[i] = __builtin_elementwise_fma(e12, v1[i], acc[i]);
                acc[i] = __builtin_elementwise_fma(e22, v2[i], acc[i]);
                acc[i] = __builtin_elementwise_fma(e32, v3[i], acc[i]);
            }
            denom += e0 + e1 + e2 + e3;
        }
    }
    // tail: quarters take strided edges
    for (int jj = j + q; jj < deg; jj += 4) {
        const int s = col[beg + jj];
        const u32x2 w = *(const u32x2*)(m + (size_t)s * FD + c0);
        f32x2 v[4];
        UNPK(w, v)
        if (MODE == 0) {
            #pragma unroll
            for (int i = 0; i < 4; ++i) acc[i] += v[i];
        } else {
            float e0 = __expf(lrelu(asrc[s] + ad));
            f32x2 e02 = {e0, e0};
            #pragma unroll
            for (int i = 0; i < 4; ++i) acc[i] = __builtin_elementwise_fma(e02, v[i], acc[i]);
            denom += e0;
        }
    }

    #pragma unroll
    for (int i = 0; i < 4; ++i) {
        float a = acc[i][0], b = acc[i][1];
        a += __shfl_xor(a, 16); a += __shfl_xor(a, 32);
        b += __shfl_xor(b, 16); b += __shfl_xor(b, 32);
        acc[i][0] = a; acc[i][1] = b;
    }
    if (MODE == 1) {
        denom += __shfl_xor(denom, 16);
        denom += __shfl_xor(denom, 32);
    }

    if (q == 0) {
        float o[8];
        #pragma unroll
        for (int i = 0; i < 8; ++i) o[i] = acc[i >> 1][i & 1];
        if (MODE == 0) {
            const float dd = dinv[d];
            u16x8 ou;
            #pragma unroll
            for (int i = 0; i < 8; ++i)
                ou[i] = f2bf(fmaxf(fmaf(dd, o[i], bias[c0 + i]), 0.f));
            *(u16x8*)((unsigned short*)outv + (size_t)d * FD + c0) = ou;
        } else {
            float inv = 1.0f / denom;
            #pragma unroll
            for (int i = 0; i < 8; ++i) o[i] *= inv;
            unsigned int lo = __builtin_amdgcn_cvt_pk_fp8_f32(o[0], o[1], 0, false);
            lo = __builtin_amdgcn_cvt_pk_fp8_f32(o[2], o[3], lo, true);
            unsigned int hi = __builtin_amdgcn_cvt_pk_fp8_f32(o[4], o[5], 0, false);
            hi = __builtin_amdgcn_cvt_pk_fp8_f32(o[6], o[7], hi, true);
            u32x2 ow = {lo, hi};
            *(u32x2*)((unsigned char*)outv + (size_t)d * FD + c0) = ow;
        }
    }
}

// ---------- mean over fp8 node outputs + final scale/bias (last-block) ----------
__global__ __launch_bounds__(256) void k_reduce(const unsigned char* __restrict__ val,
                                                float* out, const float* __restrict__ bg,
                                                int* counters, int n, float invn) {
    const int rg = threadIdx.x >> 4;
    const int cg = threadIdx.x & 15;
    const int c0 = cg * 8;
    f32x2 acc[4];
    #pragma unroll
    for (int i = 0; i < 4; ++i) acc[i] = (f32x2){0.f, 0.f};

    for (int i = blockIdx.x * 16 + rg; i < n; i += gridDim.x * 16) {
        u32x2 w = *(const u32x2*)(val + (size_t)i * FD + c0);
        f32x2 v[4];
        UNPK(w, v)
        #pragma unroll
        for (int k = 0; k < 4; ++k) acc[k] += v[k];
    }

    __shared__ float lds[16][129];
    #pragma unroll
    for (int k = 0; k < 4; ++k) {
        lds[rg][c0 + 2 * k] = acc[k][0];
        lds[rg][c0 + 2 * k + 1] = acc[k][1];
    }
    __syncthreads();
    if (threadIdx.x < 128) {
        float s = 0.f;
        #pragma unroll
        for (int k = 0; k < 16; ++k) s += lds[k][threadIdx.x];
        atomicAdd(&out[threadIdx.x], s);
    }
    __syncthreads();
    __threadfence();
    __shared__ int lastflag;
    if (threadIdx.x == 0) {
        int old = atomicAdd(&counters[0], 1);
        lastflag = (old == (int)gridDim.x - 1);
    }
    __syncthreads();
    if (lastflag) {
        __threadfence();
        if (threadIdx.x < 128) {
            float v = atomicAdd(&out[threadIdx.x], 0.0f);
            out[threadIdx.x] = v * invn + bg[threadIdx.x];
        }
    }
}

// ---------- launch ----------
extern "C" void kernel_launch(void* const* d_in, const int* in_sizes, int n_in,
                              void* d_out, int out_size, void* d_ws, size_t ws_size,
                              hipStream_t stream) {
    const float* x      = (const float*)d_in[0];
    const int*   ei     = (const int*)d_in[1];
    const float* W_emb  = (const float*)d_in[2];
    const float* b_emb  = (const float*)d_in[3];
    const float* W1     = (const float*)d_in[4];
    const float* b1     = (const float*)d_in[5];
    const float* W2     = (const float*)d_in[6];
    const float* b2     = (const float*)d_in[7];
    const float* Wg     = (const float*)d_in[8];
    const float* a_src  = (const float*)d_in[9];
    const float* a_dst  = (const float*)d_in[10];
    const float* bg     = (const float*)d_in[11];

    const int n = in_sizes[0] / FD;   // 50000
    const int e = in_sizes[1] / 2;    // 800000
    const int* src = ei;
    const int* dst = ei + e;

    unsigned short* bufB = (unsigned short*)d_ws;           // n*128 bf16 (h) / fp8 GAT out
    unsigned short* Wt4  = bufB + (size_t)n * FD;           // 3 * 128*128 bf16
    float* dinv  = (float*)(Wt4 + 3 * FD * FD);
    float* asrc  = dinv + n;
    float* adst  = asrc + n;
    int*   cnt   = (int*)(adst + n);
    int*   rp    = cnt + n;
    int*   pk    = rp + n;            // e
    int*   ghist = pk + e;            // 65536
    int*   Sg    = ghist + NB * 256;  // 65536
    int*   bsum  = Sg + NB * 256;     // 256
    int*   counters = bsum + 256;     // 2
    unsigned short* col = (unsigned short*)(counters + 2);  // e u16
    unsigned char*  bufM = (unsigned char*)(col + e);       // n*128 fp8

    const dim3 B(256);
    const int chunk  = (e + NB - 1) / NB;
    const int gnode4 = (n + 3) / 4;
    const int gb128  = (n + 127) / 128;   // 391

    // 1) mega0: emb-GEMM | bhist | wcvt | zero
    k_mega0<<<gb128 + 256 + 96 + 1, 512, 0, stream>>>(x, W_emb, b_emb, bufB,
                                                      dst, ghist, e, chunk,
                                                      W1, W2, Wg, Wt4,
                                                      (float*)d_out, counters, n, gb128);
    // 2-4) sort
    k_scan1<<<256, B, 0, stream>>>(ghist, Sg, bsum, counters, NB * 256);
    k_bscatter<<<NB, B, 0, stream>>>(dst, src, Sg, ghist, bsum, pk, e, chunk);
    k_bfinal<<<256, B, 0, stream>>>(pk, Sg, ghist, bsum, cnt, rp, dinv, col, e, n);

    // 5-6) GCN layer 1: m' = dinv * (h0 @ W1)  (fp8); h1 = relu(dinv*sum + b1) (bf16)
    k_gemm<false, true><<<gb128, 512, 0, stream>>>(bufB, Wt4 + 0 * FD * FD, bufM,
                                                   nullptr, nullptr, nullptr, nullptr, dinv, n);
    k_gather<0><<<gnode4, B, 0, stream>>>(bufM, col, rp, cnt, dinv, b1,
                                          nullptr, nullptr, bufB, n);
    // 7-8) GCN layer 2
    k_gemm<false, true><<<gb128, 512, 0, stream>>>(bufB, Wt4 + 1 * FD * FD, bufM,
                                                   nullptr, nullptr, nullptr, nullptr, dinv, n);
    k_gather<0><<<gnode4, B, 0, stream>>>(bufM, col, rp, cnt, dinv, b2,
                                          nullptr, nullptr, bufB, n);
    // 9-10) GAT: g (fp8) -> bufM; gather writes fp8 node outputs -> bufB
    k_gemm<true, false><<<gb128, 512, 0, stream>>>(bufB, Wt4 + 2 * FD * FD, bufM,
                                                   a_src, a_dst, asrc, adst, nullptr, n);
    k_gather<1><<<gnode4, B, 0, stream>>>(bufM, col, rp, cnt, nullptr, nullptr,
                                          asrc, adst, bufB, n);
    // 11) mean + final (reads fp8)
    k_reduce<<<384, B, 0, stream>>>((const unsigned char*)bufB, (float*)d_out, bg,
                                    counters, n, 1.0f / n);
}